// Round 16
// baseline (97.507 us; speedup 1.0000x reference)
//
#include <hip/hip_runtime.h>

#define BB 2
#define NN 2048
#define DD 512
#define HH 8
#define DK 64

#define LOG2E 1.44269504f
#define SCL2  0.18033688f   /* (1/8) * log2e */

typedef __attribute__((ext_vector_type(4))) float f32x4;
typedef __attribute__((ext_vector_type(16))) float f32x16;
typedef __attribute__((ext_vector_type(8))) short bf16x8;
typedef __attribute__((ext_vector_type(2))) int i32x2;
typedef __attribute__((ext_vector_type(4))) int i32x4;

__device__ __forceinline__ short f2bf(float f) {
  union { float f; unsigned u; } v; v.f = f;
  unsigned r = v.u + 0x7fffu + ((v.u >> 16) & 1u);
  return (short)(r >> 16);
}

__device__ __forceinline__ bf16x8 pack8(float4 a, float4 b) {
  bf16x8 r;
  r[0] = f2bf(a.x); r[1] = f2bf(a.y); r[2] = f2bf(a.z); r[3] = f2bf(a.w);
  r[4] = f2bf(b.x); r[5] = f2bf(b.y); r[6] = f2bf(b.z); r[7] = f2bf(b.w);
  return r;
}

#define WAITV(n) do { asm volatile("s_waitcnt vmcnt(" #n ")" ::: "memory"); \
                      __builtin_amdgcn_sched_barrier(0); } while (0)
#define GLOAD_LDS(g, l) __builtin_amdgcn_global_load_lds( \
    (const __attribute__((address_space(1))) void*)(g),   \
    (__attribute__((address_space(3))) void*)(l), 16, 0, 0)
#define SBAR() asm volatile("s_barrier" ::: "memory")
#define LDM(d, o) asm volatile("global_load_dwordx2 %0, %1, off offset:" o \
                               : "=v"(d) : "v"(mrowp))
#define CVTPK(d, a, b) asm("v_cvt_pk_bf16_f32 %0, %1, %2" : "=v"(d) : "v"(a), "v"(b))
#define PLSWAP(a, b) asm("v_permlane32_swap_b32 %0, %1" : "+v"(a), "+v"(b))

// ---------------------------------------------------------------------------
// prep: fused mask_pre + cast_pre.
// blocks 0..2047: 2 grid-stride iters of mask (8.4M elems);
// blocks 0..1535 additionally: 1 iter of cast (3.1M elems).
// ---------------------------------------------------------------------------
__global__ __launch_bounds__(256) void prep(
    const int* __restrict__ adj, const float* __restrict__ et,
    const int* __restrict__ ctp, short* __restrict__ M,
    const float* __restrict__ X,
    const float* __restrict__ wq, const float* __restrict__ wk,
    const float* __restrict__ wv, const float* __restrict__ wo,
    short* __restrict__ Xb, short* __restrict__ Wb)
{
  const float ct = (float)(*ctp);
  const float kd = -0.1f * LOG2E;
  const size_t base = ((size_t)blockIdx.x * 256 + threadIdx.x) * 8;
  const size_t stride = (size_t)2048 * 256 * 8;   // 4,194,304
#pragma unroll
  for (int it = 0; it < 2; it++) {
    const size_t i = base + (size_t)it * stride;
    int4 a0 = *(const int4*)(adj + i);
    int4 a1 = *(const int4*)(adj + i + 4);
    float4 e0 = *(const float4*)(et + i);
    float4 e1 = *(const float4*)(et + i + 4);
    const int av[8] = {a0.x, a0.y, a0.z, a0.w, a1.x, a1.y, a1.z, a1.w};
    const float ev[8] = {e0.x, e0.y, e0.z, e0.w, e1.x, e1.y, e1.z, e1.w};
    bf16x8 r;
#pragma unroll
    for (int j = 0; j < 8; j++) {
      const float tv = (av[j] == 0) ? -1.f : exp2f(kd * fmaxf(ct - ev[j], 0.f));
      r[j] = f2bf(tv);
    }
    *(bf16x8*)(M + i) = r;
  }
  if (blockIdx.x < 1536) {
    const size_t XN = (size_t)4096 * DD;          // 2,097,152
    const size_t i = base;
    const float* src;
    short* dst;
    if (i < XN) { src = X + i; dst = Xb + i; }
    else {
      const size_t j = i - XN;
      const int sel = (int)(j >> 18);
      const size_t off = j & 262143;
      src = (sel == 0 ? wq : sel == 1 ? wk : sel == 2 ? wv : wo) + off;
      dst = Wb + j;
    }
    float4 a = *(const float4*)src;
    float4 b = *(const float4*)(src + 4);
    *(bf16x8*)dst = pack8(a, b);
  }
}

// ---------------------------------------------------------------------------
// GEMM1: [Q|K|V] = Xb @ Wb^T + b (bf16). BM=128 BN=64 BK=64, global_load_lds
// staged, dbuf. Q PRE-SCALED by SCL2. (R14 structure, unchanged.)
// ---------------------------------------------------------------------------
__global__ __launch_bounds__(256, 2) void qkv_gemm(
    const short* __restrict__ Xb, const short* __restrict__ Wb,
    const float* __restrict__ bq, const float* __restrict__ bk, const float* __restrict__ bv,
    short* __restrict__ qo, short* __restrict__ ko, short* __restrict__ vto)
{
  __shared__ short As[2][128 * 64];   // 32 KB
  __shared__ short Bs[2][64 * 64];    // 16 KB

  const int tid = threadIdx.x;
  const int lane = tid & 63;
  const int w = tid >> 6;
  const int q4 = lane >> 4;
  const int c = lane & 15;

  const int bid = blockIdx.x;
  const int mt = bid & 31;
  const int nt = bid >> 5;
  const int sel = nt >> 3;
  const int nw = (nt & 7) * 64;
  const int m0 = mt * 128;
  const short* Wm = Wb + (size_t)sel * 262144;
  const float* bias = sel == 0 ? bq : (sel == 1 ? bk : bv);
  const float oscale = (sel == 0) ? SCL2 : 1.0f;

  const int sr = lane >> 3;
  const int sc = ((lane & 7) ^ sr) * 8;
  const short* ap = Xb + (size_t)(m0 + w * 32 + sr) * DD + sc;
  const short* bp = Wm + (size_t)(nw + w * 16 + sr) * DD + sc;

  f32x4 acc[2][4];
#pragma unroll
  for (int is = 0; is < 2; is++)
#pragma unroll
    for (int ns = 0; ns < 4; ns++) acc[is][ns] = f32x4{0.f, 0.f, 0.f, 0.f};

#define QSTAGE(BUF, K0)                                                    \
  { GLOAD_LDS(ap + (K0),           &As[BUF][(w * 32 + 0) * 64]);           \
    GLOAD_LDS(ap + 8 * DD + (K0),  &As[BUF][(w * 32 + 8) * 64]);           \
    GLOAD_LDS(ap + 16 * DD + (K0), &As[BUF][(w * 32 + 16) * 64]);          \
    GLOAD_LDS(ap + 24 * DD + (K0), &As[BUF][(w * 32 + 24) * 64]);          \
    GLOAD_LDS(bp + (K0),           &Bs[BUF][(w * 16 + 0) * 64]);           \
    GLOAD_LDS(bp + 8 * DD + (K0),  &Bs[BUF][(w * 16 + 8) * 64]); }

#define QCOMPUTE(BUF)                                                            \
  { const short* Asb = &As[BUF][0];                                              \
    const short* Bsb = &Bs[BUF][0];                                              \
    _Pragma("unroll") for (int kc = 0; kc < 2; kc++) {                           \
      bf16x8 af[2], bfr[4];                                                      \
      _Pragma("unroll") for (int is = 0; is < 2; is++)                           \
        af[is] = *(const bf16x8*)&Asb[(w * 32 + is * 16 + c) * 64 +              \
                                      (((kc * 4 + q4) ^ (c & 7)) * 8)];          \
      _Pragma("unroll") for (int ns = 0; ns < 4; ns++)                           \
        bfr[ns] = *(const bf16x8*)&Bsb[(ns * 16 + c) * 64 +                      \
                                       (((kc * 4 + q4) ^ (c & 7)) * 8)];         \
      _Pragma("unroll") for (int is = 0; is < 2; is++)                           \
        _Pragma("unroll") for (int ns = 0; ns < 4; ns++)                         \
          acc[is][ns] = __builtin_amdgcn_mfma_f32_16x16x32_bf16(af[is], bfr[ns], \
                                                           acc[is][ns], 0, 0, 0); \
    } }

  QSTAGE(0, 0)
  __syncthreads();
  for (int ks = 0; ks < 8; ks++) {
    if (ks < 7) QSTAGE((ks + 1) & 1, (ks + 1) * 64)
    QCOMPUTE(ks & 1)
    __syncthreads();
  }
#undef QSTAGE
#undef QCOMPUTE

#pragma unroll
  for (int ns = 0; ns < 4; ns++) {
    const int n = nw + ns * 16 + c;
    const float bval = bias[n];
    const int hh = n >> 6, d = n & 63;
#pragma unroll
    for (int is = 0; is < 2; is++)
#pragma unroll
      for (int r = 0; r < 4; r++) {
        const int m = m0 + w * 32 + is * 16 + q4 * 4 + r;
        const int bb = m >> 11, tok = m & 2047;
        const float val = (acc[is][ns][r] + bval) * oscale;
        if (sel == 2)      vto[((size_t)(bb * HH + hh) * DK + d) * NN + tok] = f2bf(val);
        else if (sel == 1) ko [((size_t)(bb * HH + hh) * NN + tok) * DK + d] = f2bf(val);
        else               qo [((size_t)(bb * HH + hh) * NN + tok) * DK + d] = f2bf(val);
      }
  }
}

// ---------------------------------------------------------------------------
// Flash attention: 4-wave blocks (128 q-rows), grid 1024 = 4 blocks/CU (4
// independent barrier groups; R13 was 2). Same per-wave math as R13: j-split
// x4, 32KB block K/V LDS dbuf, mask dbuf, swapped 32x32 MFMA, in-register P,
// permlane32_swap, setprio. NEW: hoisted LDS read addresses (ka/va regs +
// compile-time ds offsets -> zero in-loop address VALU). FIFO vmcnt: [S:4]+
// [MU:8]; WAITV(12)/WAITV(12); peeled last WAITV(8)/WAITV(0).
// ---------------------------------------------------------------------------
__global__ __launch_bounds__(256, 2) void attn_kernel(
    const short* __restrict__ qt, const short* __restrict__ kt, const short* __restrict__ vtt,
    const short* __restrict__ M,
    const float* __restrict__ wt,
    short* __restrict__ po_out, float* __restrict__ pl_out)
{
  __shared__ short Ks[2][64 * 64];    // 16 KB (K tile dbuf)
  __shared__ short Vs[2][64 * 64];    // 16 KB (V^T tile dbuf)

  const int tid = threadIdx.x;
  const int lane = tid & 63;
  const int w = tid >> 6;          // wave 0..3
  const int l31 = lane & 31;
  const int hi = lane >> 5;
  const int l7 = l31 & 7;

  // decode: xcd = bid&7 = b*4 + jsp; rest: h (0..7), qblk (0..15)
  const int bid = blockIdx.x;
  const int xcd = bid & 7;
  const int b = xcd >> 2;
  const int jsp = xcd & 3;
  const int rest = bid >> 3;        // 0..127
  const int h = rest & 7;
  const int qblk = rest >> 3;       // 0..15
  const int i0w = qblk * 128 + w * 32;
  const int jbase = jsp * 512;

  const float wth2 = wt[h] * LOG2E;

  const short* qb = qt + ((size_t)(b * HH + h) * NN + i0w) * DK;
  const short* kb = kt + (size_t)(b * HH + h) * NN * DK;
  const short* vb = vtt + (size_t)(b * HH + h) * DK * NN;
  const short* mrowp = M + ((size_t)b * NN + i0w + l31) * NN + jbase + hi * 4;

  // Q fragments (B operand): col i = l31, k = kc*16 + hi*8 + e
  bf16x8 aq[4];
#pragma unroll
  for (int kc = 0; kc < 4; kc++)
    aq[kc] = *(const bf16x8*)(qb + l31 * DK + kc * 16 + hi * 8);
  asm volatile("" :: "v"(aq[0]), "v"(aq[1]), "v"(aq[2]), "v"(aq[3]), "v"(wth2));
  WAITV(0);   // drain compiler-issued loads; counted sequence starts clean

  // hoisted LDS read byte-offsets (per-lane, loop-invariant)
  unsigned ka[4], va[4];
#pragma unroll
  for (int kc = 0; kc < 4; kc++)
    ka[kc] = (unsigned)(l31 * 128 + (((kc * 2 + hi) ^ l7) * 16));
#pragma unroll
  for (int jc = 0; jc < 4; jc++) {  // jc = js*2 + ch
    const int js = jc >> 1, ch = jc & 1;
    va[jc] = (unsigned)(l31 * 128 + (((js * 4 + ch * 2 + hi) ^ l7) * 16));
  }

  float lp = 0.f;
  f32x16 oacc[2];
#pragma unroll
  for (int ds = 0; ds < 2; ds++)
#pragma unroll
    for (int r = 0; r < 16; r++) oacc[ds][r] = 0.f;

  // staging sources (pre-swizzled): wave w stages K rows w*16..+15, V^T rows w*16..+15
  const int srow = lane >> 3;
  const int ssw = ((lane & 7) ^ srow) * 8;
  const short* kp0 = kb + (size_t)(jbase + w * 16 + srow) * DK + ssw;
  const short* kp1 = kp0 + 8 * DK;
  const short* vp0 = vb + (size_t)(w * 16 + srow) * NN + jbase + ssw;
  const short* vp1 = vp0 + 8 * NN;
  const char* KsB = (const char*)&Ks[0][0];
  const char* VsB = (const char*)&Vs[0][0];

#define STAGE(BUFN)                                                        \
  { GLOAD_LDS(kp0, &Ks[BUFN][(w * 16) * 64]);                              \
    GLOAD_LDS(kp1, &Ks[BUFN][(w * 16 + 8) * 64]);                          \
    GLOAD_LDS(vp0, &Vs[BUFN][(w * 16) * 64]);                              \
    GLOAD_LDS(vp1, &Vs[BUFN][(w * 16 + 8) * 64]);                          \
    __builtin_amdgcn_sched_barrier(0); }

#define KADV() { kp0 += 64 * DK; kp1 += 64 * DK; vp0 += 64; vp1 += 64; }
#define MADV() { mrowp += 64; }

#define ISSUE_MASK(MU)                                                     \
  { LDM(MU[0][0], "0");  LDM(MU[0][1], "16"); LDM(MU[0][2], "32");  LDM(MU[0][3], "48");  \
    LDM(MU[1][0], "64"); LDM(MU[1][1], "80"); LDM(MU[1][2], "96");  LDM(MU[1][3], "112"); \
    __builtin_amdgcn_sched_barrier(0); }

  i32x2 muA[2][4], muB[2][4];

  // prologue: [S0:4, muA:8]
  STAGE(0)
  KADV()
  ISSUE_MASK(muA)
  MADV()

#define COMPUTE_QK(BUFC)                                                         \
    f32x16 sacc[2];                                                              \
    __builtin_amdgcn_s_setprio(1);                                               \
    _Pragma("unroll") for (int js = 0; js < 2; js++) {                           \
      _Pragma("unroll") for (int r = 0; r < 16; r++) sacc[js][r] = 0.f;          \
      _Pragma("unroll") for (int kc = 0; kc < 4; kc++) {                         \
        bf16x8 kf = *(const bf16x8*)(KsB + (BUFC) * 8192 + js * 4096 + ka[kc]);  \
        sacc[js] = __builtin_amdgcn_mfma_f32_32x32x16_bf16(kf, aq[kc],           \
                                                           sacc[js], 0, 0, 0);   \
      }                                                                          \
    }                                                                            \
    __builtin_amdgcn_s_setprio(0);

#define COMPUTE_SM_PV(BUFC, MU)                                                  \
    __builtin_amdgcn_s_setprio(1);                                               \
    _Pragma("unroll") for (int js = 0; js < 2; js++) {                           \
      float p[16];                                                               \
      _Pragma("unroll") for (int r = 0; r < 16; r++) {                           \
        const int dw = ((r & 3) < 2) ? MU[js][r >> 2][0] : MU[js][r >> 2][1];    \
        union { float f; unsigned u; } tu;                                       \
        tu.u = (r & 1) ? ((unsigned)dw & 0xffff0000u) : ((unsigned)dw << 16);    \
        const float tv = tu.f;                                                   \
        const float pp = exp2f(fmaf(tv, wth2, sacc[js][r]));                     \
        p[r] = (tv < 0.f) ? 0.f : pp;                                            \
        lp += p[r];                                                              \
      }                                                                          \
      bf16x8 pf[2];                                                              \
      _Pragma("unroll") for (int ch = 0; ch < 2; ch++) {                         \
        const int rb = ch * 8;                                                   \
        int w0, w1, w2, w3;                                                      \
        CVTPK(w0, p[rb + 0], p[rb + 1]);                                         \
        CVTPK(w1, p[rb + 2], p[rb + 3]);                                         \
        CVTPK(w2, p[rb + 4], p[rb + 5]);                                         \
        CVTPK(w3, p[rb + 6], p[rb + 7]);                                         \
        PLSWAP(w0, w2);                                                          \
        PLSWAP(w1, w3);                                                          \
        i32x4 bi;                                                                \
        bi[0] = w0; bi[1] = w1; bi[2] = w2; bi[3] = w3;                          \
        union { i32x4 i; bf16x8 h; } cv; cv.i = bi;                              \
        pf[ch] = cv.h;                                                           \
      }                                                                          \
      _Pragma("unroll") for (int ds = 0; ds < 2; ds++) {                         \
        _Pragma("unroll") for (int ch = 0; ch < 2; ch++) {                       \
          bf16x8 vf = *(const bf16x8*)(VsB + (BUFC) * 8192 + ds * 4096 +         \
                                       va[js * 2 + ch]);                         \
          oacc[ds] = __builtin_amdgcn_mfma_f32_32x32x16_bf16(vf, pf[ch],         \
                                                             oacc[ds], 0, 0, 0); \
        }                                                                        \
      }                                                                          \
    }                                                                            \
    __builtin_amdgcn_s_setprio(0);

  // iteration: entry [S_t:4, MUC:8]
#define ATTN_ITER(T, MUC, MUN)                                                   \
  {                                                                              \
    STAGE(((T) + 1) & 1)         /* [S_t:4, MUC:8, S_t1:4] = 16 */               \
    KADV()                                                                       \
    WAITV(12);                   /* drain S_t; [MUC:8, S_t1:4] */                \
    SBAR();                                                                      \
    COMPUTE_QK((T) & 1)                                                          \
    ISSUE_MASK(MUN)              /* [MUC:8, S_t1:4, MUN:8] = 20 */               \
    MADV()                                                                       \
    WAITV(12);                   /* drain MUC; [S_t1:4, MUN:8] */                \
    COMPUTE_SM_PV((T) & 1, MUC)                                                  \
    SBAR();                                                                      \
  }

  for (int t2 = 0; t2 < 3; t2++) {
    ATTN_ITER(2 * t2,     muA, muB)
    ATTN_ITER(2 * t2 + 1, muB, muA)
  }
  ATTN_ITER(6, muA, muB)
  {
    // peeled t=7: entry [S7:4, muB:8]
    WAITV(8);                    // drain S7
    SBAR();
    COMPUTE_QK(1)
    WAITV(0);                    // drain muB
    COMPUTE_SM_PV(1, muB)
  }

#undef ATTN_ITER
#undef COMPUTE_QK
#undef COMPUTE_SM_PV
#undef STAGE
#undef KADV
#undef MADV
#undef ISSUE_MASK

  // epilogue: partial row sum (own half + partner half), store UNNORMALIZED
  const float lt = lp + __shfl_xor(lp, 32);
  const size_t ridx = ((size_t)(jsp * BB + b) * HH + h) * NN + i0w + l31;
  if (lane < 32) pl_out[ridx] = lt;
  short* pob = po_out + ridx * DK;
#pragma unroll
  for (int ds = 0; ds < 2; ds++)
#pragma unroll
    for (int r = 0; r < 16; r++) {
      const int d = ds * 32 + (r & 3) + 8 * (r >> 2) + 4 * hi;
      pob[d] = f2bf(oacc[ds][r]);
    }
}

// ---------------------------------------------------------------------------
// combine: AO[b][n][h*64+d] = sum_jsp PO / sum_jsp PL   (4 partials)
// ---------------------------------------------------------------------------
__global__ __launch_bounds__(256) void combine(
    const short* __restrict__ PO, const float* __restrict__ PL,
    short* __restrict__ AO)
{
  const int g = blockIdx.x * 256 + threadIdx.x;     // 0..262143
  const int t8 = g & 7;
  const int h  = (g >> 3) & 7;
  const int n  = (g >> 6) & 2047;
  const int b  = g >> 17;
  float acc[8] = {0.f, 0.f, 0.f, 0.f, 0.f, 0.f, 0.f, 0.f};
  float ls = 0.f;
#pragma unroll
  for (int jp = 0; jp < 4; jp++) {
    const size_t ridx = ((size_t)(jp * BB + b) * HH + h) * NN + n;
    bf16x8 v = *(const bf16x8*)(PO + ridx * DK + t8 * 8);
    ls += PL[ridx];
#pragma unroll
    for (int e = 0; e < 8; e++) {
      union { float f; unsigned u; } cv;
      cv.u = ((unsigned)(unsigned short)v[e]) << 16;
      acc[e] += cv.f;
    }
  }
  const float rl = 1.0f / ls;
  bf16x8 o;
#pragma unroll
  for (int e = 0; e < 8; e++) o[e] = f2bf(acc[e] * rl);
  *(bf16x8*)(AO + (size_t)g * 8) = o;
}

// ---------------------------------------------------------------------------
// GEMM2: out = AO @ wo^T + bo + nf. (R14 structure, unchanged.)
// ---------------------------------------------------------------------------
__global__ __launch_bounds__(256, 2) void out_gemm(
    const short* __restrict__ AO, const short* __restrict__ wob, const float* __restrict__ bo,
    const float* __restrict__ nf, float* __restrict__ out)
{
  __shared__ short As[2][128 * 64];   // 32 KB
  __shared__ short Bs[2][64 * 64];    // 16 KB

  const int tid = threadIdx.x;
  const int lane = tid & 63;
  const int w = tid >> 6;
  const int q4 = lane >> 4;
  const int c = lane & 15;

  const int bid = blockIdx.x;
  const int mt = bid & 31;
  const int n0 = (bid >> 5) * 64;
  const int m0 = mt * 128;

  const int sr = lane >> 3;
  const int sc = ((lane & 7) ^ sr) * 8;
  const short* ap = AO + (size_t)(m0 + w * 32 + sr) * DD + sc;
  const short* bp = wob + (size_t)(n0 + w * 16 + sr) * DD + sc;

  f32x4 acc[2][4];
#pragma unroll
  for (int is = 0; is < 2; is++)
#pragma unroll
    for (int ns = 0; ns < 4; ns++) acc[is][ns] = f32x4{0.f, 0.f, 0.f, 0.f};

#define OSTAGE(BUF, K0)                                                    \
  { GLOAD_LDS(ap + (K0),           &As[BUF][(w * 32 + 0) * 64]);           \
    GLOAD_LDS(ap + 8 * DD + (K0),  &As[BUF][(w * 32 + 8) * 64]);           \
    GLOAD_LDS(ap + 16 * DD + (K0), &As[BUF][(w * 32 + 16) * 64]);          \
    GLOAD_LDS(ap + 24 * DD + (K0), &As[BUF][(w * 32 + 24) * 64]);          \
    GLOAD_LDS(bp + (K0),           &Bs[BUF][(w * 16 + 0) * 64]);           \
    GLOAD_LDS(bp + 8 * DD + (K0),  &Bs[BUF][(w * 16 + 8) * 64]); }

#define OCOMPUTE(BUF)                                                            \
  { const short* Asb = &As[BUF][0];                                              \
    const short* Bsb = &Bs[BUF][0];                                              \
    _Pragma("unroll") for (int kc = 0; kc < 2; kc++) {                           \
      bf16x8 af[2], bfr[4];                                                      \
      _Pragma("unroll") for (int is = 0; is < 2; is++)                           \
        af[is] = *(const bf16x8*)&Asb[(w * 32 + is * 16 + c) * 64 +              \
                                      (((kc * 4 + q4) ^ (c & 7)) * 8)];          \
      _Pragma("unroll") for (int ns = 0; ns < 4; ns++)                           \
        bfr[ns] = *(const bf16x8*)&Bsb[(ns * 16 + c) * 64 +                      \
                                       (((kc * 4 + q4) ^ (c & 7)) * 8)];         \
      _Pragma("unroll") for (int is = 0; is < 2; is++)                           \
        _Pragma("unroll") for (int ns = 0; ns < 4; ns++)                         \
          acc[is][ns] = __builtin_amdgcn_mfma_f32_16x16x32_bf16(af[is], bfr[ns], \
                                                           acc[is][ns], 0, 0, 0); \
    } }

  OSTAGE(0, 0)
  __syncthreads();
  for (int ks = 0; ks < 8; ks++) {
    if (ks < 7) OSTAGE((ks + 1) & 1, (ks + 1) * 64)
    OCOMPUTE(ks & 1)
    __syncthreads();
  }
#undef OSTAGE
#undef OCOMPUTE

#pragma unroll
  for (int ns = 0; ns < 4; ns++) {
    const int n = n0 + ns * 16 + c;
    const float bval = bo[n];
#pragma unroll
    for (int is = 0; is < 2; is++)
#pragma unroll
      for (int r = 0; r < 4; r++) {
        const int m = m0 + w * 32 + is * 16 + q4 * 4 + r;
        out[(size_t)m * DD + n] = acc[is][ns][r] + bval + nf[(size_t)m * DD + n];
      }
  }
}

extern "C" void kernel_launch(void* const* d_in, const int* in_sizes, int n_in,
                              void* d_out, int out_size, void* d_ws, size_t ws_size,
                              hipStream_t stream) {
  const float* nf  = (const float*)d_in[0];
  const int*   adj = (const int*)d_in[1];
  const float* et  = (const float*)d_in[2];
  const int*   ct  = (const int*)d_in[3];
  const float* wq  = (const float*)d_in[4];
  const float* bq  = (const float*)d_in[5];
  const float* wk  = (const float*)d_in[6];
  const float* bk  = (const float*)d_in[7];
  const float* wv  = (const float*)d_in[8];
  const float* bv  = (const float*)d_in[9];
  const float* wo  = (const float*)d_in[10];
  const float* bo  = (const float*)d_in[11];
  const float* wt  = (const float*)d_in[12];

  const size_t SZ = (size_t)BB * HH * NN * DK;  // 2,097,152 elements
  short* q   = (short*)d_ws;
  short* k   = q + SZ;
  short* vt  = k + SZ;
  short* ao  = vt + SZ;
  short* Mm  = ao + SZ;                         // BB*NN*NN bf16 = 16.8 MB
  short* PO  = Mm + (size_t)BB * NN * NN;       // 4*SZ bf16 = 16.8 MB
  float* PL  = (float*)(PO + 4 * SZ);           // 4*BB*HH*NN f32 = 0.5 MB
  short* Xb  = (short*)(PL + 4 * BB * HH * NN); // 4096*512 bf16 = 4.2 MB
  short* Wb  = Xb + (size_t)4096 * DD;          // 4*512*512 bf16 = 2.1 MB

  prep<<<2048, 256, 0, stream>>>(adj, et, ct, Mm, nf, wq, wk, wv, wo, Xb, Wb);
  qkv_gemm<<<768, 256, 0, stream>>>(Xb, Wb, bq, bk, bv, q, k, vt);
  attn_kernel<<<1024, 256, 0, stream>>>(q, k, vt, Mm, wt, PO, PL);
  combine<<<1024, 256, 0, stream>>>(PO, PL, ao);
  out_gemm<<<256, 256, 0, stream>>>(ao, Wb + 3 * 262144, bo, nf, (float*)d_out);
}

// Round 17
// 95.766 us; speedup vs baseline: 1.0182x; 1.0182x over previous
//
#include <hip/hip_runtime.h>

#define BB 2
#define NN 2048
#define DD 512
#define HH 8
#define DK 64

#define LOG2E 1.44269504f
#define SCL2  0.18033688f   /* (1/8) * log2e */

typedef __attribute__((ext_vector_type(4))) float f32x4;
typedef __attribute__((ext_vector_type(16))) float f32x16;
typedef __attribute__((ext_vector_type(8))) short bf16x8;
typedef __attribute__((ext_vector_type(2))) int i32x2;
typedef __attribute__((ext_vector_type(4))) int i32x4;

__device__ __forceinline__ short f2bf(float f) {
  union { float f; unsigned u; } v; v.f = f;
  unsigned r = v.u + 0x7fffu + ((v.u >> 16) & 1u);
  return (short)(r >> 16);
}

__device__ __forceinline__ bf16x8 pack8(float4 a, float4 b) {
  bf16x8 r;
  r[0] = f2bf(a.x); r[1] = f2bf(a.y); r[2] = f2bf(a.z); r[3] = f2bf(a.w);
  r[4] = f2bf(b.x); r[5] = f2bf(b.y); r[6] = f2bf(b.z); r[7] = f2bf(b.w);
  return r;
}

#define WAITV(n) do { asm volatile("s_waitcnt vmcnt(" #n ")" ::: "memory"); \
                      __builtin_amdgcn_sched_barrier(0); } while (0)
#define GLOAD_LDS(g, l) __builtin_amdgcn_global_load_lds( \
    (const __attribute__((address_space(1))) void*)(g),   \
    (__attribute__((address_space(3))) void*)(l), 16, 0, 0)
#define SBAR() asm volatile("s_barrier" ::: "memory")
#define LDM(d, o) asm volatile("global_load_dwordx2 %0, %1, off offset:" o \
                               : "=v"(d) : "v"(mrowp))
#define CVTPK(d, a, b) asm("v_cvt_pk_bf16_f32 %0, %1, %2" : "=v"(d) : "v"(a), "v"(b))
#define PLSWAP(a, b) asm("v_permlane32_swap_b32 %0, %1" : "+v"(a), "+v"(b))

// ---------------------------------------------------------------------------
// prep: fused mask_pre + cast_pre (R16, unchanged).
// ---------------------------------------------------------------------------
__global__ __launch_bounds__(256) void prep(
    const int* __restrict__ adj, const float* __restrict__ et,
    const int* __restrict__ ctp, short* __restrict__ M,
    const float* __restrict__ X,
    const float* __restrict__ wq, const float* __restrict__ wk,
    const float* __restrict__ wv, const float* __restrict__ wo,
    short* __restrict__ Xb, short* __restrict__ Wb)
{
  const float ct = (float)(*ctp);
  const float kd = -0.1f * LOG2E;
  const size_t base = ((size_t)blockIdx.x * 256 + threadIdx.x) * 8;
  const size_t stride = (size_t)2048 * 256 * 8;   // 4,194,304
#pragma unroll
  for (int it = 0; it < 2; it++) {
    const size_t i = base + (size_t)it * stride;
    int4 a0 = *(const int4*)(adj + i);
    int4 a1 = *(const int4*)(adj + i + 4);
    float4 e0 = *(const float4*)(et + i);
    float4 e1 = *(const float4*)(et + i + 4);
    const int av[8] = {a0.x, a0.y, a0.z, a0.w, a1.x, a1.y, a1.z, a1.w};
    const float ev[8] = {e0.x, e0.y, e0.z, e0.w, e1.x, e1.y, e1.z, e1.w};
    bf16x8 r;
#pragma unroll
    for (int j = 0; j < 8; j++) {
      const float tv = (av[j] == 0) ? -1.f : exp2f(kd * fmaxf(ct - ev[j], 0.f));
      r[j] = f2bf(tv);
    }
    *(bf16x8*)(M + i) = r;
  }
  if (blockIdx.x < 1536) {
    const size_t XN = (size_t)4096 * DD;          // 2,097,152
    const size_t i = base;
    const float* src;
    short* dst;
    if (i < XN) { src = X + i; dst = Xb + i; }
    else {
      const size_t j = i - XN;
      const int sel = (int)(j >> 18);
      const size_t off = j & 262143;
      src = (sel == 0 ? wq : sel == 1 ? wk : sel == 2 ? wv : wo) + off;
      dst = Wb + j;
    }
    float4 a = *(const float4*)src;
    float4 b = *(const float4*)(src + 4);
    *(bf16x8*)dst = pack8(a, b);
  }
}

// ---------------------------------------------------------------------------
// GEMM1 (R14/R16 structure, unchanged).
// ---------------------------------------------------------------------------
__global__ __launch_bounds__(256, 2) void qkv_gemm(
    const short* __restrict__ Xb, const short* __restrict__ Wb,
    const float* __restrict__ bq, const float* __restrict__ bk, const float* __restrict__ bv,
    short* __restrict__ qo, short* __restrict__ ko, short* __restrict__ vto)
{
  __shared__ short As[2][128 * 64];   // 32 KB
  __shared__ short Bs[2][64 * 64];    // 16 KB

  const int tid = threadIdx.x;
  const int lane = tid & 63;
  const int w = tid >> 6;
  const int q4 = lane >> 4;
  const int c = lane & 15;

  const int bid = blockIdx.x;
  const int mt = bid & 31;
  const int nt = bid >> 5;
  const int sel = nt >> 3;
  const int nw = (nt & 7) * 64;
  const int m0 = mt * 128;
  const short* Wm = Wb + (size_t)sel * 262144;
  const float* bias = sel == 0 ? bq : (sel == 1 ? bk : bv);
  const float oscale = (sel == 0) ? SCL2 : 1.0f;

  const int sr = lane >> 3;
  const int sc = ((lane & 7) ^ sr) * 8;
  const short* ap = Xb + (size_t)(m0 + w * 32 + sr) * DD + sc;
  const short* bp = Wm + (size_t)(nw + w * 16 + sr) * DD + sc;

  f32x4 acc[2][4];
#pragma unroll
  for (int is = 0; is < 2; is++)
#pragma unroll
    for (int ns = 0; ns < 4; ns++) acc[is][ns] = f32x4{0.f, 0.f, 0.f, 0.f};

#define QSTAGE(BUF, K0)                                                    \
  { GLOAD_LDS(ap + (K0),           &As[BUF][(w * 32 + 0) * 64]);           \
    GLOAD_LDS(ap + 8 * DD + (K0),  &As[BUF][(w * 32 + 8) * 64]);           \
    GLOAD_LDS(ap + 16 * DD + (K0), &As[BUF][(w * 32 + 16) * 64]);          \
    GLOAD_LDS(ap + 24 * DD + (K0), &As[BUF][(w * 32 + 24) * 64]);          \
    GLOAD_LDS(bp + (K0),           &Bs[BUF][(w * 16 + 0) * 64]);           \
    GLOAD_LDS(bp + 8 * DD + (K0),  &Bs[BUF][(w * 16 + 8) * 64]); }

#define QCOMPUTE(BUF)                                                            \
  { const short* Asb = &As[BUF][0];                                              \
    const short* Bsb = &Bs[BUF][0];                                              \
    _Pragma("unroll") for (int kc = 0; kc < 2; kc++) {                           \
      bf16x8 af[2], bfr[4];                                                      \
      _Pragma("unroll") for (int is = 0; is < 2; is++)                           \
        af[is] = *(const bf16x8*)&Asb[(w * 32 + is * 16 + c) * 64 +              \
                                      (((kc * 4 + q4) ^ (c & 7)) * 8)];          \
      _Pragma("unroll") for (int ns = 0; ns < 4; ns++)                           \
        bfr[ns] = *(const bf16x8*)&Bsb[(ns * 16 + c) * 64 +                      \
                                       (((kc * 4 + q4) ^ (c & 7)) * 8)];         \
      _Pragma("unroll") for (int is = 0; is < 2; is++)                           \
        _Pragma("unroll") for (int ns = 0; ns < 4; ns++)                         \
          acc[is][ns] = __builtin_amdgcn_mfma_f32_16x16x32_bf16(af[is], bfr[ns], \
                                                           acc[is][ns], 0, 0, 0); \
    } }

  QSTAGE(0, 0)
  __syncthreads();
  for (int ks = 0; ks < 8; ks++) {
    if (ks < 7) QSTAGE((ks + 1) & 1, (ks + 1) * 64)
    QCOMPUTE(ks & 1)
    __syncthreads();
  }
#undef QSTAGE
#undef QCOMPUTE

#pragma unroll
  for (int ns = 0; ns < 4; ns++) {
    const int n = nw + ns * 16 + c;
    const float bval = bias[n];
    const int hh = n >> 6, d = n & 63;
#pragma unroll
    for (int is = 0; is < 2; is++)
#pragma unroll
      for (int r = 0; r < 4; r++) {
        const int m = m0 + w * 32 + is * 16 + q4 * 4 + r;
        const int bb = m >> 11, tok = m & 2047;
        const float val = (acc[is][ns][r] + bval) * oscale;
        if (sel == 2)      vto[((size_t)(bb * HH + hh) * DK + d) * NN + tok] = f2bf(val);
        else if (sel == 1) ko [((size_t)(bb * HH + hh) * NN + tok) * DK + d] = f2bf(val);
        else               qo [((size_t)(bb * HH + hh) * NN + tok) * DK + d] = f2bf(val);
      }
  }
}

// ---------------------------------------------------------------------------
// Flash attention: KVBLK=128, ONE s_barrier per tile (4 total vs 16).
// 8-wave blocks (512 thr), grid 512, 64KB LDS K/V dbuf. Two mask half-buffers
// (muA=js0-1, muB=js2-3), FIFO-exact counted vmcnt; dbuf makes the leading
// barrier redundant (stage drained by each wave pre-SBAR). Swapped 32x32
// MFMA, in-register P, permlane32_swap, setprio — R16 math verbatim.
// ---------------------------------------------------------------------------
__global__ __launch_bounds__(512, 2) void attn_kernel(
    const short* __restrict__ qt, const short* __restrict__ kt, const short* __restrict__ vtt,
    const short* __restrict__ M,
    const float* __restrict__ wt,
    short* __restrict__ po_out, float* __restrict__ pl_out)
{
  __shared__ short Ks[2][128 * 64];   // 32 KB (K tile dbuf: 128 j-rows x 64 dk)
  __shared__ short Vs[2][64 * 128];   // 32 KB (V^T tile dbuf: 64 dk-rows x 128 j)

  const int tid = threadIdx.x;
  const int lane = tid & 63;
  const int w = tid >> 6;          // wave 0..7
  const int l31 = lane & 31;
  const int hi = lane >> 5;
  const int l7 = l31 & 7;

  // decode: xcd = bid&7 = b*4 + jsp; rest: h (0..7), qblk (0..7)
  const int bid = blockIdx.x;
  const int xcd = bid & 7;
  const int b = xcd >> 2;
  const int jsp = xcd & 3;
  const int rest = bid >> 3;        // 0..63
  const int h = rest & 7;
  const int qblk = rest >> 3;       // 0..7
  const int i0w = qblk * 256 + w * 32;
  const int jbase = jsp * 512;

  const float wth2 = wt[h] * LOG2E;

  const short* qb = qt + ((size_t)(b * HH + h) * NN + i0w) * DK;
  const short* kb = kt + (size_t)(b * HH + h) * NN * DK;
  const short* vb = vtt + (size_t)(b * HH + h) * DK * NN;
  const short* mrowp = M + ((size_t)b * NN + i0w + l31) * NN + jbase + hi * 4;

  // Q fragments (B operand): col i = l31, k = kc*16 + hi*8 + e
  bf16x8 aq[4];
#pragma unroll
  for (int kc = 0; kc < 4; kc++)
    aq[kc] = *(const bf16x8*)(qb + l31 * DK + kc * 16 + hi * 8);
  asm volatile("" :: "v"(aq[0]), "v"(aq[1]), "v"(aq[2]), "v"(aq[3]), "v"(wth2));
  WAITV(0);   // drain compiler-issued loads; counted sequence starts clean

  // hoisted LDS read byte-offsets (loop-invariant)
  unsigned ka[4];
#pragma unroll
  for (int kc = 0; kc < 4; kc++)
    ka[kc] = (unsigned)(l31 * 128 + (((kc * 2 + hi) ^ l7) * 16));
  unsigned va2[8];
#pragma unroll
  for (int jc = 0; jc < 8; jc++) {   // jc = js*2 + ch, js 0..3
    const int js = jc >> 1, ch = jc & 1;
    va2[jc] = (unsigned)(l31 * 256 + (((js * 4 + ch * 2 + hi) ^ (l31 & 15)) * 16));
  }

  float lp = 0.f;
  f32x16 oacc[2];
#pragma unroll
  for (int ds = 0; ds < 2; ds++)
#pragma unroll
    for (int r = 0; r < 16; r++) oacc[ds][r] = 0.f;

  // staging sources (pre-swizzled)
  const int kr = w * 16 + (lane >> 3);           // K j-row within tile
  const short* kp0 = kb + (size_t)(jbase + kr) * DK + (((lane & 7) ^ (kr & 7)) * 8);
  const short* kp1 = kp0 + 8 * DK;               // (kr+8)&7 == kr&7
  const int vr = w * 8 + (lane >> 4);            // V^T dk-row
  const short* vp0 = vb + (size_t)vr * NN + jbase + (((lane & 15) ^ (vr & 15)) * 8);
  const short* vp1 = vb + (size_t)(vr + 4) * NN + jbase + (((lane & 15) ^ ((vr + 4) & 15)) * 8);
  const char* KsB = (const char*)&Ks[0][0];
  const char* VsB = (const char*)&Vs[0][0];

#define STAGE(BUFN)                                                        \
  { GLOAD_LDS(kp0, &Ks[BUFN][(w * 16) * 64]);                              \
    GLOAD_LDS(kp1, &Ks[BUFN][(w * 16 + 8) * 64]);                          \
    GLOAD_LDS(vp0, &Vs[BUFN][(w * 8) * 128]);                              \
    GLOAD_LDS(vp1, &Vs[BUFN][(w * 8 + 4) * 128]);                          \
    __builtin_amdgcn_sched_barrier(0); }

#define KADV() { kp0 += 128 * DK; kp1 += 128 * DK; vp0 += 128; vp1 += 128; }
#define MADV() { mrowp += 128; }

#define ISSUE_MASK_H0(MU)                                                  \
  { LDM(MU[0][0], "0");  LDM(MU[0][1], "16"); LDM(MU[0][2], "32");  LDM(MU[0][3], "48");  \
    LDM(MU[1][0], "64"); LDM(MU[1][1], "80"); LDM(MU[1][2], "96");  LDM(MU[1][3], "112"); \
    __builtin_amdgcn_sched_barrier(0); }
#define ISSUE_MASK_H1(MU)                                                  \
  { LDM(MU[0][0], "128"); LDM(MU[0][1], "144"); LDM(MU[0][2], "160"); LDM(MU[0][3], "176"); \
    LDM(MU[1][0], "192"); LDM(MU[1][1], "208"); LDM(MU[1][2], "224"); LDM(MU[1][3], "240"); \
    __builtin_amdgcn_sched_barrier(0); }

  i32x2 muA[2][4], muB[2][4];

  // prologue: stage tile0 [4] + masks tile0-half0 [8]; drain stage; barrier
  STAGE(0)
  KADV()
  ISSUE_MASK_H0(muA)
  WAITV(8);
  SBAR();

#define COMPUTE_QK(BUFC, JS0)                                                    \
    __builtin_amdgcn_s_setprio(1);                                               \
    _Pragma("unroll") for (int jj = 0; jj < 2; jj++) {                           \
      _Pragma("unroll") for (int r = 0; r < 16; r++) sacc[jj][r] = 0.f;          \
      _Pragma("unroll") for (int kc = 0; kc < 4; kc++) {                         \
        bf16x8 kf = *(const bf16x8*)(KsB + (BUFC) * 16384 +                      \
                                     ((JS0) + jj) * 4096 + ka[kc]);              \
        sacc[jj] = __builtin_amdgcn_mfma_f32_32x32x16_bf16(kf, aq[kc],           \
                                                           sacc[jj], 0, 0, 0);   \
      }                                                                          \
    }                                                                            \
    __builtin_amdgcn_s_setprio(0);

#define COMPUTE_SM_PV(BUFC, MU, JS0)                                             \
    __builtin_amdgcn_s_setprio(1);                                               \
    _Pragma("unroll") for (int jj = 0; jj < 2; jj++) {                           \
      float p[16];                                                               \
      _Pragma("unroll") for (int r = 0; r < 16; r++) {                           \
        const int dw = ((r & 3) < 2) ? MU[jj][r >> 2][0] : MU[jj][r >> 2][1];    \
        union { float f; unsigned u; } tu;                                       \
        tu.u = (r & 1) ? ((unsigned)dw & 0xffff0000u) : ((unsigned)dw << 16);    \
        const float tv = tu.f;                                                   \
        const float pp = exp2f(fmaf(tv, wth2, sacc[jj][r]));                     \
        p[r] = (tv < 0.f) ? 0.f : pp;                                            \
        lp += p[r];                                                              \
      }                                                                          \
      bf16x8 pf[2];                                                              \
      _Pragma("unroll") for (int ch = 0; ch < 2; ch++) {                         \
        const int rb = ch * 8;                                                   \
        int w0, w1, w2, w3;                                                      \
        CVTPK(w0, p[rb + 0], p[rb + 1]);                                         \
        CVTPK(w1, p[rb + 2], p[rb + 3]);                                         \
        CVTPK(w2, p[rb + 4], p[rb + 5]);                                         \
        CVTPK(w3, p[rb + 6], p[rb + 7]);                                         \
        PLSWAP(w0, w2);                                                          \
        PLSWAP(w1, w3);                                                          \
        i32x4 bi;                                                                \
        bi[0] = w0; bi[1] = w1; bi[2] = w2; bi[3] = w3;                          \
        union { i32x4 i; bf16x8 h; } cv; cv.i = bi;                              \
        pf[ch] = cv.h;                                                           \
      }                                                                          \
      _Pragma("unroll") for (int ds = 0; ds < 2; ds++) {                         \
        _Pragma("unroll") for (int ch = 0; ch < 2; ch++) {                       \
          bf16x8 vf = *(const bf16x8*)(VsB + (BUFC) * 16384 + ds * 8192 +        \
                                       va2[((JS0) + jj) * 2 + ch]);              \
          oacc[ds] = __builtin_amdgcn_mfma_f32_32x32x16_bf16(vf, pf[ch],         \
                                                             oacc[ds], 0, 0, 0); \
        }                                                                        \
      }                                                                          \
    }                                                                            \
    __builtin_amdgcn_s_setprio(0);

  // iteration (entry: [muA:8], buf T&1 staged+visible); ONE barrier per tile
#define ATTN_ITER(T, LASTI)                                                      \
  {                                                                              \
    f32x16 sacc[2];                                                              \
    if (!(LASTI)) { STAGE(((T) + 1) & 1) KADV() }   /* [muA:8, S:4] */           \
    COMPUTE_QK((T) & 1, 0)                                                       \
    ISSUE_MASK_H1(muB)            /* [muA:8, S:4, muB:8] = 20 (last: 16) */      \
    if (LASTI) { WAITV(8); } else { WAITV(12); }     /* drain muA */             \
    COMPUTE_SM_PV((T) & 1, muA, 0)                                               \
    COMPUTE_QK((T) & 1, 2)                                                       \
    if (!(LASTI)) { MADV() ISSUE_MASK_H0(muA) }  /* [S:4, muB:8, muA':8] */      \
    if (LASTI) { WAITV(0); } else { WAITV(8); }      /* drain S + muB */         \
    COMPUTE_SM_PV((T) & 1, muB, 2)                                               \
    if (!(LASTI)) { SBAR(); }                                                    \
  }

  ATTN_ITER(0, 0)
  ATTN_ITER(1, 0)
  ATTN_ITER(2, 0)
  ATTN_ITER(3, 1)

#undef ATTN_ITER
#undef COMPUTE_QK
#undef COMPUTE_SM_PV
#undef STAGE
#undef KADV
#undef MADV
#undef ISSUE_MASK_H0
#undef ISSUE_MASK_H1

  // epilogue: partial row sum (own half + partner half), store UNNORMALIZED
  const float lt = lp + __shfl_xor(lp, 32);
  const size_t ridx = ((size_t)(jsp * BB + b) * HH + h) * NN + i0w + l31;
  if (lane < 32) pl_out[ridx] = lt;
  short* pob = po_out + ridx * DK;
#pragma unroll
  for (int ds = 0; ds < 2; ds++)
#pragma unroll
    for (int r = 0; r < 16; r++) {
      const int d = ds * 32 + (r & 3) + 8 * (r >> 2) + 4 * hi;
      pob[d] = f2bf(oacc[ds][r]);
    }
}

// ---------------------------------------------------------------------------
// combine: AO[b][n][h*64+d] = sum_jsp PO / sum_jsp PL   (4 partials)
// ---------------------------------------------------------------------------
__global__ __launch_bounds__(256) void combine(
    const short* __restrict__ PO, const float* __restrict__ PL,
    short* __restrict__ AO)
{
  const int g = blockIdx.x * 256 + threadIdx.x;     // 0..262143
  const int t8 = g & 7;
  const int h  = (g >> 3) & 7;
  const int n  = (g >> 6) & 2047;
  const int b  = g >> 17;
  float acc[8] = {0.f, 0.f, 0.f, 0.f, 0.f, 0.f, 0.f, 0.f};
  float ls = 0.f;
#pragma unroll
  for (int jp = 0; jp < 4; jp++) {
    const size_t ridx = ((size_t)(jp * BB + b) * HH + h) * NN + n;
    bf16x8 v = *(const bf16x8*)(PO + ridx * DK + t8 * 8);
    ls += PL[ridx];
#pragma unroll
    for (int e = 0; e < 8; e++) {
      union { float f; unsigned u; } cv;
      cv.u = ((unsigned)(unsigned short)v[e]) << 16;
      acc[e] += cv.f;
    }
  }
  const float rl = 1.0f / ls;
  bf16x8 o;
#pragma unroll
  for (int e = 0; e < 8; e++) o[e] = f2bf(acc[e] * rl);
  *(bf16x8*)(AO + (size_t)g * 8) = o;
}

// ---------------------------------------------------------------------------
// GEMM2 (R14/R16 structure, unchanged).
// ---------------------------------------------------------------------------
__global__ __launch_bounds__(256, 2) void out_gemm(
    const short* __restrict__ AO, const short* __restrict__ wob, const float* __restrict__ bo,
    const float* __restrict__ nf, float* __restrict__ out)
{
  __shared__ short As[2][128 * 64];   // 32 KB
  __shared__ short Bs[2][64 * 64];    // 16 KB

  const int tid = threadIdx.x;
  const int lane = tid & 63;
  const int w = tid >> 6;
  const int q4 = lane >> 4;
  const int c = lane & 15;

  const int bid = blockIdx.x;
  const int mt = bid & 31;
  const int n0 = (bid >> 5) * 64;
  const int m0 = mt * 128;

  const int sr = lane >> 3;
  const int sc = ((lane & 7) ^ sr) * 8;
  const short* ap = AO + (size_t)(m0 + w * 32 + sr) * DD + sc;
  const short* bp = wob + (size_t)(n0 + w * 16 + sr) * DD + sc;

  f32x4 acc[2][4];
#pragma unroll
  for (int is = 0; is < 2; is++)
#pragma unroll
    for (int ns = 0; ns < 4; ns++) acc[is][ns] = f32x4{0.f, 0.f, 0.f, 0.f};

#define OSTAGE(BUF, K0)                                                    \
  { GLOAD_LDS(ap + (K0),           &As[BUF][(w * 32 + 0) * 64]);           \
    GLOAD_LDS(ap + 8 * DD + (K0),  &As[BUF][(w * 32 + 8) * 64]);           \
    GLOAD_LDS(ap + 16 * DD + (K0), &As[BUF][(w * 32 + 16) * 64]);          \
    GLOAD_LDS(ap + 24 * DD + (K0), &As[BUF][(w * 32 + 24) * 64]);          \
    GLOAD_LDS(bp + (K0),           &Bs[BUF][(w * 16 + 0) * 64]);           \
    GLOAD_LDS(bp + 8 * DD + (K0),  &Bs[BUF][(w * 16 + 8) * 64]); }

#define OCOMPUTE(BUF)                                                            \
  { const short* Asb = &As[BUF][0];                                              \
    const short* Bsb = &Bs[BUF][0];                                              \
    _Pragma("unroll") for (int kc = 0; kc < 2; kc++) {                           \
      bf16x8 af[2], bfr[4];                                                      \
      _Pragma("unroll") for (int is = 0; is < 2; is++)                           \
        af[is] = *(const bf16x8*)&Asb[(w * 32 + is * 16 + c) * 64 +              \
                                      (((kc * 4 + q4) ^ (c & 7)) * 8)];          \
      _Pragma("unroll") for (int ns = 0; ns < 4; ns++)                           \
        bfr[ns] = *(const bf16x8*)&Bsb[(ns * 16 + c) * 64 +                      \
                                       (((kc * 4 + q4) ^ (c & 7)) * 8)];         \
      _Pragma("unroll") for (int is = 0; is < 2; is++)                           \
        _Pragma("unroll") for (int ns = 0; ns < 4; ns++)                         \
          acc[is][ns] = __builtin_amdgcn_mfma_f32_16x16x32_bf16(af[is], bfr[ns], \
                                                           acc[is][ns], 0, 0, 0); \
    } }

  OSTAGE(0, 0)
  __syncthreads();
  for (int ks = 0; ks < 8; ks++) {
    if (ks < 7) OSTAGE((ks + 1) & 1, (ks + 1) * 64)
    OCOMPUTE(ks & 1)
    __syncthreads();
  }
#undef OSTAGE
#undef OCOMPUTE

#pragma unroll
  for (int ns = 0; ns < 4; ns++) {
    const int n = n0 + ns * 16 + c;
    const float bval = bo[n];
#pragma unroll
    for (int is = 0; is < 2; is++)
#pragma unroll
      for (int r = 0; r < 4; r++) {
        const int m = m0 + w * 32 + is * 16 + q4 * 4 + r;
        out[(size_t)m * DD + n] = acc[is][ns][r] + bval + nf[(size_t)m * DD + n];
      }
  }
}

extern "C" void kernel_launch(void* const* d_in, const int* in_sizes, int n_in,
                              void* d_out, int out_size, void* d_ws, size_t ws_size,
                              hipStream_t stream) {
  const float* nf  = (const float*)d_in[0];
  const int*   adj = (const int*)d_in[1];
  const float* et  = (const float*)d_in[2];
  const int*   ct  = (const int*)d_in[3];
  const float* wq  = (const float*)d_in[4];
  const float* bq  = (const float*)d_in[5];
  const float* wk  = (const float*)d_in[6];
  const float* bk  = (const float*)d_in[7];
  const float* wv  = (const float*)d_in[8];
  const float* bv  = (const float*)d_in[9];
  const float* wo  = (const float*)d_in[10];
  const float* bo  = (const float*)d_in[11];
  const float* wt  = (const float*)d_in[12];

  const size_t SZ = (size_t)BB * HH * NN * DK;  // 2,097,152 elements
  short* q   = (short*)d_ws;
  short* k   = q + SZ;
  short* vt  = k + SZ;
  short* ao  = vt + SZ;
  short* Mm  = ao + SZ;                         // BB*NN*NN bf16 = 16.8 MB
  short* PO  = Mm + (size_t)BB * NN * NN;       // 4*SZ bf16 = 16.8 MB
  float* PL  = (float*)(PO + 4 * SZ);           // 4*BB*HH*NN f32 = 0.5 MB
  short* Xb  = (short*)(PL + 4 * BB * HH * NN); // 4096*512 bf16 = 4.2 MB
  short* Wb  = Xb + (size_t)4096 * DD;          // 4*512*512 bf16 = 2.1 MB

  prep<<<2048, 256, 0, stream>>>(adj, et, ct, Mm, nf, wq, wk, wv, wo, Xb, Wb);
  qkv_gemm<<<768, 256, 0, stream>>>(Xb, Wb, bq, bk, bv, q, k, vt);
  attn_kernel<<<512, 512, 0, stream>>>(q, k, vt, Mm, wt, PO, PL);
  combine<<<1024, 256, 0, stream>>>(PO, PL, ao);
  out_gemm<<<256, 256, 0, stream>>>(ao, Wb + 3 * 262144, bo, nf, (float*)d_out);
}

// Round 18
// 92.201 us; speedup vs baseline: 1.0575x; 1.0387x over previous
//
#include <hip/hip_runtime.h>

#define BB 2
#define NN 2048
#define DD 512
#define HH 8
#define DK 64

#define LOG2E 1.44269504f
#define SCL2  0.18033688f   /* (1/8) * log2e */

typedef __attribute__((ext_vector_type(4))) float f32x4;
typedef __attribute__((ext_vector_type(16))) float f32x16;
typedef __attribute__((ext_vector_type(8))) short bf16x8;
typedef __attribute__((ext_vector_type(2))) int i32x2;
typedef __attribute__((ext_vector_type(4))) int i32x4;

__device__ __forceinline__ short f2bf(float f) {
  union { float f; unsigned u; } v; v.f = f;
  unsigned r = v.u + 0x7fffu + ((v.u >> 16) & 1u);
  return (short)(r >> 16);
}

__device__ __forceinline__ bf16x8 pack8(float4 a, float4 b) {
  bf16x8 r;
  r[0] = f2bf(a.x); r[1] = f2bf(a.y); r[2] = f2bf(a.z); r[3] = f2bf(a.w);
  r[4] = f2bf(b.x); r[5] = f2bf(b.y); r[6] = f2bf(b.z); r[7] = f2bf(b.w);
  return r;
}

#define WAITV(n) do { asm volatile("s_waitcnt vmcnt(" #n ")" ::: "memory"); \
                      __builtin_amdgcn_sched_barrier(0); } while (0)
#define GLOAD_LDS(g, l) __builtin_amdgcn_global_load_lds( \
    (const __attribute__((address_space(1))) void*)(g),   \
    (__attribute__((address_space(3))) void*)(l), 16, 0, 0)
#define SBAR() asm volatile("s_barrier" ::: "memory")
#define LDM4(d, o) asm volatile("global_load_dwordx4 %0, %1, off offset:" o \
                                : "=v"(d) : "v"(mrowp))
#define CVTPK(d, a, b) asm("v_cvt_pk_bf16_f32 %0, %1, %2" : "=v"(d) : "v"(a), "v"(b))
#define PLSWAP(a, b) asm("v_permlane32_swap_b32 %0, %1" : "+v"(a), "+v"(b))

// ---------------------------------------------------------------------------
// prep: fused mask_pre + cast_pre (R16, unchanged).
// ---------------------------------------------------------------------------
__global__ __launch_bounds__(256) void prep(
    const int* __restrict__ adj, const float* __restrict__ et,
    const int* __restrict__ ctp, short* __restrict__ M,
    const float* __restrict__ X,
    const float* __restrict__ wq, const float* __restrict__ wk,
    const float* __restrict__ wv, const float* __restrict__ wo,
    short* __restrict__ Xb, short* __restrict__ Wb)
{
  const float ct = (float)(*ctp);
  const float kd = -0.1f * LOG2E;
  const size_t base = ((size_t)blockIdx.x * 256 + threadIdx.x) * 8;
  const size_t stride = (size_t)2048 * 256 * 8;   // 4,194,304
#pragma unroll
  for (int it = 0; it < 2; it++) {
    const size_t i = base + (size_t)it * stride;
    int4 a0 = *(const int4*)(adj + i);
    int4 a1 = *(const int4*)(adj + i + 4);
    float4 e0 = *(const float4*)(et + i);
    float4 e1 = *(const float4*)(et + i + 4);
    const int av[8] = {a0.x, a0.y, a0.z, a0.w, a1.x, a1.y, a1.z, a1.w};
    const float ev[8] = {e0.x, e0.y, e0.z, e0.w, e1.x, e1.y, e1.z, e1.w};
    bf16x8 r;
#pragma unroll
    for (int j = 0; j < 8; j++) {
      const float tv = (av[j] == 0) ? -1.f : exp2f(kd * fmaxf(ct - ev[j], 0.f));
      r[j] = f2bf(tv);
    }
    *(bf16x8*)(M + i) = r;
  }
  if (blockIdx.x < 1536) {
    const size_t XN = (size_t)4096 * DD;          // 2,097,152
    const size_t i = base;
    const float* src;
    short* dst;
    if (i < XN) { src = X + i; dst = Xb + i; }
    else {
      const size_t j = i - XN;
      const int sel = (int)(j >> 18);
      const size_t off = j & 262143;
      src = (sel == 0 ? wq : sel == 1 ? wk : sel == 2 ? wv : wo) + off;
      dst = Wb + j;
    }
    float4 a = *(const float4*)src;
    float4 b = *(const float4*)(src + 4);
    *(bf16x8*)dst = pack8(a, b);
  }
}

// ---------------------------------------------------------------------------
// GEMM1 (R14/R16 structure, unchanged).
// ---------------------------------------------------------------------------
__global__ __launch_bounds__(256, 2) void qkv_gemm(
    const short* __restrict__ Xb, const short* __restrict__ Wb,
    const float* __restrict__ bq, const float* __restrict__ bk, const float* __restrict__ bv,
    short* __restrict__ qo, short* __restrict__ ko, short* __restrict__ vto)
{
  __shared__ short As[2][128 * 64];   // 32 KB
  __shared__ short Bs[2][64 * 64];    // 16 KB

  const int tid = threadIdx.x;
  const int lane = tid & 63;
  const int w = tid >> 6;
  const int q4 = lane >> 4;
  const int c = lane & 15;

  const int bid = blockIdx.x;
  const int mt = bid & 31;
  const int nt = bid >> 5;
  const int sel = nt >> 3;
  const int nw = (nt & 7) * 64;
  const int m0 = mt * 128;
  const short* Wm = Wb + (size_t)sel * 262144;
  const float* bias = sel == 0 ? bq : (sel == 1 ? bk : bv);
  const float oscale = (sel == 0) ? SCL2 : 1.0f;

  const int sr = lane >> 3;
  const int sc = ((lane & 7) ^ sr) * 8;
  const short* ap = Xb + (size_t)(m0 + w * 32 + sr) * DD + sc;
  const short* bp = Wm + (size_t)(nw + w * 16 + sr) * DD + sc;

  f32x4 acc[2][4];
#pragma unroll
  for (int is = 0; is < 2; is++)
#pragma unroll
    for (int ns = 0; ns < 4; ns++) acc[is][ns] = f32x4{0.f, 0.f, 0.f, 0.f};

#define QSTAGE(BUF, K0)                                                    \
  { GLOAD_LDS(ap + (K0),           &As[BUF][(w * 32 + 0) * 64]);           \
    GLOAD_LDS(ap + 8 * DD + (K0),  &As[BUF][(w * 32 + 8) * 64]);           \
    GLOAD_LDS(ap + 16 * DD + (K0), &As[BUF][(w * 32 + 16) * 64]);          \
    GLOAD_LDS(ap + 24 * DD + (K0), &As[BUF][(w * 32 + 24) * 64]);          \
    GLOAD_LDS(bp + (K0),           &Bs[BUF][(w * 16 + 0) * 64]);           \
    GLOAD_LDS(bp + 8 * DD + (K0),  &Bs[BUF][(w * 16 + 8) * 64]); }

#define QCOMPUTE(BUF)                                                            \
  { const short* Asb = &As[BUF][0];                                              \
    const short* Bsb = &Bs[BUF][0];                                              \
    _Pragma("unroll") for (int kc = 0; kc < 2; kc++) {                           \
      bf16x8 af[2], bfr[4];                                                      \
      _Pragma("unroll") for (int is = 0; is < 2; is++)                           \
        af[is] = *(const bf16x8*)&Asb[(w * 32 + is * 16 + c) * 64 +              \
                                      (((kc * 4 + q4) ^ (c & 7)) * 8)];          \
      _Pragma("unroll") for (int ns = 0; ns < 4; ns++)                           \
        bfr[ns] = *(const bf16x8*)&Bsb[(ns * 16 + c) * 64 +                      \
                                       (((kc * 4 + q4) ^ (c & 7)) * 8)];         \
      _Pragma("unroll") for (int is = 0; is < 2; is++)                           \
        _Pragma("unroll") for (int ns = 0; ns < 4; ns++)                         \
          acc[is][ns] = __builtin_amdgcn_mfma_f32_16x16x32_bf16(af[is], bfr[ns], \
                                                           acc[is][ns], 0, 0, 0); \
    } }

  QSTAGE(0, 0)
  __syncthreads();
  for (int ks = 0; ks < 8; ks++) {
    if (ks < 7) QSTAGE((ks + 1) & 1, (ks + 1) * 64)
    QCOMPUTE(ks & 1)
    __syncthreads();
  }
#undef QSTAGE
#undef QCOMPUTE

#pragma unroll
  for (int ns = 0; ns < 4; ns++) {
    const int n = nw + ns * 16 + c;
    const float bval = bias[n];
    const int hh = n >> 6, d = n & 63;
#pragma unroll
    for (int is = 0; is < 2; is++)
#pragma unroll
      for (int r = 0; r < 4; r++) {
        const int m = m0 + w * 32 + is * 16 + q4 * 4 + r;
        const int bb = m >> 11, tok = m & 2047;
        const float val = (acc[is][ns][r] + bval) * oscale;
        if (sel == 2)      vto[((size_t)(bb * HH + hh) * DK + d) * NN + tok] = f2bf(val);
        else if (sel == 1) ko [((size_t)(bb * HH + hh) * NN + tok) * DK + d] = f2bf(val);
        else               qo [((size_t)(bb * HH + hh) * NN + tok) * DK + d] = f2bf(val);
      }
  }
}

// ---------------------------------------------------------------------------
// Flash attention: R17 structure (KVBLK=128, 1 barrier/tile, 8-wave blocks,
// grid 512, 64KB LDS K/V dbuf) + dwordx4 mask loads (8/tile, was 16) +
// packed dwordx2 epilogue stores (8/wave, was 32 scalar).
// FIFO: entry [muA:4]; STAGE:4 -> QK01 -> muB:4 -> vmcnt(8) -> SMPV01+QK23
// -> muA':4 -> vmcnt(4) -> SMPV23 -> SBAR.
// ---------------------------------------------------------------------------
__global__ __launch_bounds__(512, 2) void attn_kernel(
    const short* __restrict__ qt, const short* __restrict__ kt, const short* __restrict__ vtt,
    const short* __restrict__ M,
    const float* __restrict__ wt,
    short* __restrict__ po_out, float* __restrict__ pl_out)
{
  __shared__ short Ks[2][128 * 64];   // 32 KB (K tile dbuf: 128 j-rows x 64 dk)
  __shared__ short Vs[2][64 * 128];   // 32 KB (V^T tile dbuf: 64 dk-rows x 128 j)

  const int tid = threadIdx.x;
  const int lane = tid & 63;
  const int w = tid >> 6;          // wave 0..7
  const int l31 = lane & 31;
  const int hi = lane >> 5;
  const int l7 = l31 & 7;

  // decode: xcd = bid&7 = b*4 + jsp; rest: h (0..7), qblk (0..7)
  const int bid = blockIdx.x;
  const int xcd = bid & 7;
  const int b = xcd >> 2;
  const int jsp = xcd & 3;
  const int rest = bid >> 3;        // 0..63
  const int h = rest & 7;
  const int qblk = rest >> 3;       // 0..7
  const int i0w = qblk * 256 + w * 32;
  const int jbase = jsp * 512;

  const float wth2 = wt[h] * LOG2E;

  const short* qb = qt + ((size_t)(b * HH + h) * NN + i0w) * DK;
  const short* kb = kt + (size_t)(b * HH + h) * NN * DK;
  const short* vb = vtt + (size_t)(b * HH + h) * DK * NN;
  const short* mrowp = M + ((size_t)b * NN + i0w + l31) * NN + jbase + hi * 4;

  // Q fragments (B operand): col i = l31, k = kc*16 + hi*8 + e
  bf16x8 aq[4];
#pragma unroll
  for (int kc = 0; kc < 4; kc++)
    aq[kc] = *(const bf16x8*)(qb + l31 * DK + kc * 16 + hi * 8);
  asm volatile("" :: "v"(aq[0]), "v"(aq[1]), "v"(aq[2]), "v"(aq[3]), "v"(wth2));
  WAITV(0);   // drain compiler-issued loads; counted sequence starts clean

  // hoisted LDS read byte-offsets (loop-invariant)
  unsigned ka[4];
#pragma unroll
  for (int kc = 0; kc < 4; kc++)
    ka[kc] = (unsigned)(l31 * 128 + (((kc * 2 + hi) ^ l7) * 16));
  unsigned va2[8];
#pragma unroll
  for (int jc = 0; jc < 8; jc++) {   // jc = js*2 + ch, js 0..3
    const int js = jc >> 1, ch = jc & 1;
    va2[jc] = (unsigned)(l31 * 256 + (((js * 4 + ch * 2 + hi) ^ (l31 & 15)) * 16));
  }

  float lp = 0.f;
  f32x16 oacc[2];
#pragma unroll
  for (int ds = 0; ds < 2; ds++)
#pragma unroll
    for (int r = 0; r < 16; r++) oacc[ds][r] = 0.f;

  // staging sources (pre-swizzled)
  const int kr = w * 16 + (lane >> 3);           // K j-row within tile
  const short* kp0 = kb + (size_t)(jbase + kr) * DK + (((lane & 7) ^ (kr & 7)) * 8);
  const short* kp1 = kp0 + 8 * DK;               // (kr+8)&7 == kr&7
  const int vr = w * 8 + (lane >> 4);            // V^T dk-row
  const short* vp0 = vb + (size_t)vr * NN + jbase + (((lane & 15) ^ (vr & 15)) * 8);
  const short* vp1 = vb + (size_t)(vr + 4) * NN + jbase + (((lane & 15) ^ ((vr + 4) & 15)) * 8);
  const char* KsB = (const char*)&Ks[0][0];
  const char* VsB = (const char*)&Vs[0][0];

#define STAGE(BUFN)                                                        \
  { GLOAD_LDS(kp0, &Ks[BUFN][(w * 16) * 64]);                              \
    GLOAD_LDS(kp1, &Ks[BUFN][(w * 16 + 8) * 64]);                          \
    GLOAD_LDS(vp0, &Vs[BUFN][(w * 8) * 128]);                              \
    GLOAD_LDS(vp1, &Vs[BUFN][(w * 8 + 4) * 128]);                          \
    __builtin_amdgcn_sched_barrier(0); }

#define KADV() { kp0 += 128 * DK; kp1 += 128 * DK; vp0 += 128; vp1 += 128; }
#define MADV() { mrowp += 128; }

// masks: 4 x dwordx4 per half; MU[jj][qq] covers q = 2qq, 2qq+1
#define ISSUE_MASK_H0(MU)                                                  \
  { LDM4(MU[0][0], "0");   LDM4(MU[0][1], "32");                           \
    LDM4(MU[1][0], "64");  LDM4(MU[1][1], "96");                           \
    __builtin_amdgcn_sched_barrier(0); }
#define ISSUE_MASK_H1(MU)                                                  \
  { LDM4(MU[0][0], "128"); LDM4(MU[0][1], "160");                          \
    LDM4(MU[1][0], "192"); LDM4(MU[1][1], "224");                          \
    __builtin_amdgcn_sched_barrier(0); }

  i32x4 muA[2][2], muB[2][2];

  // prologue: stage tile0 [4] + masks tile0-half0 [4]; drain stage; barrier
  STAGE(0)
  KADV()
  ISSUE_MASK_H0(muA)
  WAITV(4);
  SBAR();

#define COMPUTE_QK(BUFC, JS0)                                                    \
    __builtin_amdgcn_s_setprio(1);                                               \
    _Pragma("unroll") for (int jj = 0; jj < 2; jj++) {                           \
      _Pragma("unroll") for (int r = 0; r < 16; r++) sacc[jj][r] = 0.f;          \
      _Pragma("unroll") for (int kc = 0; kc < 4; kc++) {                         \
        bf16x8 kf = *(const bf16x8*)(KsB + (BUFC) * 16384 +                      \
                                     ((JS0) + jj) * 4096 + ka[kc]);              \
        sacc[jj] = __builtin_amdgcn_mfma_f32_32x32x16_bf16(kf, aq[kc],           \
                                                           sacc[jj], 0, 0, 0);   \
      }                                                                          \
    }                                                                            \
    __builtin_amdgcn_s_setprio(0);

#define COMPUTE_SM_PV(BUFC, MU, JS0)                                             \
    __builtin_amdgcn_s_setprio(1);                                               \
    _Pragma("unroll") for (int jj = 0; jj < 2; jj++) {                           \
      float p[16];                                                               \
      _Pragma("unroll") for (int r = 0; r < 16; r++) {                           \
        const int q = r >> 2;                                                    \
        const int dw = MU[jj][q >> 1][(q & 1) * 2 + ((r & 3) >> 1)];             \
        union { float f; unsigned u; } tu;                                       \
        tu.u = (r & 1) ? ((unsigned)dw & 0xffff0000u) : ((unsigned)dw << 16);    \
        const float tv = tu.f;                                                   \
        const float pp = exp2f(fmaf(tv, wth2, sacc[jj][r]));                     \
        p[r] = (tv < 0.f) ? 0.f : pp;                                            \
        lp += p[r];                                                              \
      }                                                                          \
      bf16x8 pf[2];                                                              \
      _Pragma("unroll") for (int ch = 0; ch < 2; ch++) {                         \
        const int rb = ch * 8;                                                   \
        int w0, w1, w2, w3;                                                      \
        CVTPK(w0, p[rb + 0], p[rb + 1]);                                         \
        CVTPK(w1, p[rb + 2], p[rb + 3]);                                         \
        CVTPK(w2, p[rb + 4], p[rb + 5]);                                         \
        CVTPK(w3, p[rb + 6], p[rb + 7]);                                         \
        PLSWAP(w0, w2);                                                          \
        PLSWAP(w1, w3);                                                          \
        i32x4 bi;                                                                \
        bi[0] = w0; bi[1] = w1; bi[2] = w2; bi[3] = w3;                          \
        union { i32x4 i; bf16x8 h; } cv; cv.i = bi;                              \
        pf[ch] = cv.h;                                                           \
      }                                                                          \
      _Pragma("unroll") for (int ds = 0; ds < 2; ds++) {                         \
        _Pragma("unroll") for (int ch = 0; ch < 2; ch++) {                       \
          bf16x8 vf = *(const bf16x8*)(VsB + (BUFC) * 16384 + ds * 8192 +        \
                                       va2[((JS0) + jj) * 2 + ch]);              \
          oacc[ds] = __builtin_amdgcn_mfma_f32_32x32x16_bf16(vf, pf[ch],         \
                                                             oacc[ds], 0, 0, 0); \
        }                                                                        \
      }                                                                          \
    }                                                                            \
    __builtin_amdgcn_s_setprio(0);

  // iteration (entry: [muA:4], buf T&1 staged+visible); ONE barrier per tile
#define ATTN_ITER(T, LASTI)                                                      \
  {                                                                              \
    f32x16 sacc[2];                                                              \
    if (!(LASTI)) { STAGE(((T) + 1) & 1) KADV() }   /* [muA:4, S:4] */           \
    COMPUTE_QK((T) & 1, 0)                                                       \
    ISSUE_MASK_H1(muB)            /* [muA:4, S:4, muB:4] = 12 (last: 8) */       \
    if (LASTI) { WAITV(4); } else { WAITV(8); }      /* drain muA */             \
    COMPUTE_SM_PV((T) & 1, muA, 0)                                               \
    COMPUTE_QK((T) & 1, 2)                                                       \
    if (!(LASTI)) { MADV() ISSUE_MASK_H0(muA) }  /* [S:4, muB:4, muA':4] */      \
    if (LASTI) { WAITV(0); } else { WAITV(4); }      /* drain S + muB */         \
    COMPUTE_SM_PV((T) & 1, muB, 2)                                               \
    if (!(LASTI)) { SBAR(); }                                                    \
  }

  ATTN_ITER(0, 0)
  ATTN_ITER(1, 0)
  ATTN_ITER(2, 0)
  ATTN_ITER(3, 1)

#undef ATTN_ITER
#undef COMPUTE_QK
#undef COMPUTE_SM_PV
#undef STAGE
#undef KADV
#undef MADV
#undef ISSUE_MASK_H0
#undef ISSUE_MASK_H1

  // epilogue: partial row sum; packed dwordx2 stores of UNNORMALIZED O^T
  const float lt = lp + __shfl_xor(lp, 32);
  const size_t ridx = ((size_t)(jsp * BB + b) * HH + h) * NN + i0w + l31;
  if (lane < 32) pl_out[ridx] = lt;
  short* pob = po_out + ridx * DK;
#pragma unroll
  for (int ds = 0; ds < 2; ds++)
#pragma unroll
    for (int q = 0; q < 4; q++) {
      int d0, d1;
      CVTPK(d0, oacc[ds][q * 4 + 0], oacc[ds][q * 4 + 1]);
      CVTPK(d1, oacc[ds][q * 4 + 2], oacc[ds][q * 4 + 3]);
      i32x2 pk; pk[0] = d0; pk[1] = d1;
      *(i32x2*)(pob + ds * 32 + q * 8 + hi * 4) = pk;
    }
}

// ---------------------------------------------------------------------------
// combine: AO[b][n][h*64+d] = sum_jsp PO / sum_jsp PL   (4 partials)
// ---------------------------------------------------------------------------
__global__ __launch_bounds__(256) void combine(
    const short* __restrict__ PO, const float* __restrict__ PL,
    short* __restrict__ AO)
{
  const int g = blockIdx.x * 256 + threadIdx.x;     // 0..262143
  const int t8 = g & 7;
  const int h  = (g >> 3) & 7;
  const int n  = (g >> 6) & 2047;
  const int b  = g >> 17;
  float acc[8] = {0.f, 0.f, 0.f, 0.f, 0.f, 0.f, 0.f, 0.f};
  float ls = 0.f;
#pragma unroll
  for (int jp = 0; jp < 4; jp++) {
    const size_t ridx = ((size_t)(jp * BB + b) * HH + h) * NN + n;
    bf16x8 v = *(const bf16x8*)(PO + ridx * DK + t8 * 8);
    ls += PL[ridx];
#pragma unroll
    for (int e = 0; e < 8; e++) {
      union { float f; unsigned u; } cv;
      cv.u = ((unsigned)(unsigned short)v[e]) << 16;
      acc[e] += cv.f;
    }
  }
  const float rl = 1.0f / ls;
  bf16x8 o;
#pragma unroll
  for (int e = 0; e < 8; e++) o[e] = f2bf(acc[e] * rl);
  *(bf16x8*)(AO + (size_t)g * 8) = o;
}

// ---------------------------------------------------------------------------
// GEMM2 (R14/R16 structure, unchanged).
// ---------------------------------------------------------------------------
__global__ __launch_bounds__(256, 2) void out_gemm(
    const short* __restrict__ AO, const short* __restrict__ wob, const float* __restrict__ bo,
    const float* __restrict__ nf, float* __restrict__ out)
{
  __shared__ short As[2][128 * 64];   // 32 KB
  __shared__ short Bs[2][64 * 64];    // 16 KB

  const int tid = threadIdx.x;
  const int lane = tid & 63;
  const int w = tid >> 6;
  const int q4 = lane >> 4;
  const int c = lane & 15;

  const int bid = blockIdx.x;
  const int mt = bid & 31;
  const int n0 = (bid >> 5) * 64;
  const int m0 = mt * 128;

  const int sr = lane >> 3;
  const int sc = ((lane & 7) ^ sr) * 8;
  const short* ap = AO + (size_t)(m0 + w * 32 + sr) * DD + sc;
  const short* bp = wob + (size_t)(n0 + w * 16 + sr) * DD + sc;

  f32x4 acc[2][4];
#pragma unroll
  for (int is = 0; is < 2; is++)
#pragma unroll
    for (int ns = 0; ns < 4; ns++) acc[is][ns] = f32x4{0.f, 0.f, 0.f, 0.f};

#define OSTAGE(BUF, K0)                                                    \
  { GLOAD_LDS(ap + (K0),           &As[BUF][(w * 32 + 0) * 64]);           \
    GLOAD_LDS(ap + 8 * DD + (K0),  &As[BUF][(w * 32 + 8) * 64]);           \
    GLOAD_LDS(ap + 16 * DD + (K0), &As[BUF][(w * 32 + 16) * 64]);          \
    GLOAD_LDS(ap + 24 * DD + (K0), &As[BUF][(w * 32 + 24) * 64]);          \
    GLOAD_LDS(bp + (K0),           &Bs[BUF][(w * 16 + 0) * 64]);           \
    GLOAD_LDS(bp + 8 * DD + (K0),  &Bs[BUF][(w * 16 + 8) * 64]); }

#define OCOMPUTE(BUF)                                                            \
  { const short* Asb = &As[BUF][0];                                              \
    const short* Bsb = &Bs[BUF][0];                                              \
    _Pragma("unroll") for (int kc = 0; kc < 2; kc++) {                           \
      bf16x8 af[2], bfr[4];                                                      \
      _Pragma("unroll") for (int is = 0; is < 2; is++)                           \
        af[is] = *(const bf16x8*)&Asb[(w * 32 + is * 16 + c) * 64 +              \
                                      (((kc * 4 + q4) ^ (c & 7)) * 8)];          \
      _Pragma("unroll") for (int ns = 0; ns < 4; ns++)                           \
        bfr[ns] = *(const bf16x8*)&Bsb[(ns * 16 + c) * 64 +                      \
                                       (((kc * 4 + q4) ^ (c & 7)) * 8)];         \
      _Pragma("unroll") for (int is = 0; is < 2; is++)                           \
        _Pragma("unroll") for (int ns = 0; ns < 4; ns++)                         \
          acc[is][ns] = __builtin_amdgcn_mfma_f32_16x16x32_bf16(af[is], bfr[ns], \
                                                           acc[is][ns], 0, 0, 0); \
    } }

  OSTAGE(0, 0)
  __syncthreads();
  for (int ks = 0; ks < 8; ks++) {
    if (ks < 7) OSTAGE((ks + 1) & 1, (ks + 1) * 64)
    OCOMPUTE(ks & 1)
    __syncthreads();
  }
#undef OSTAGE
#undef OCOMPUTE

#pragma unroll
  for (int ns = 0; ns < 4; ns++) {
    const int n = n0 + ns * 16 + c;
    const float bval = bo[n];
#pragma unroll
    for (int is = 0; is < 2; is++)
#pragma unroll
      for (int r = 0; r < 4; r++) {
        const int m = m0 + w * 32 + is * 16 + q4 * 4 + r;
        out[(size_t)m * DD + n] = acc[is][ns][r] + bval + nf[(size_t)m * DD + n];
      }
  }
}

extern "C" void kernel_launch(void* const* d_in, const int* in_sizes, int n_in,
                              void* d_out, int out_size, void* d_ws, size_t ws_size,
                              hipStream_t stream) {
  const float* nf  = (const float*)d_in[0];
  const int*   adj = (const int*)d_in[1];
  const float* et  = (const float*)d_in[2];
  const int*   ct  = (const int*)d_in[3];
  const float* wq  = (const float*)d_in[4];
  const float* bq  = (const float*)d_in[5];
  const float* wk  = (const float*)d_in[6];
  const float* bk  = (const float*)d_in[7];
  const float* wv  = (const float*)d_in[8];
  const float* bv  = (const float*)d_in[9];
  const float* wo  = (const float*)d_in[10];
  const float* bo  = (const float*)d_in[11];
  const float* wt  = (const float*)d_in[12];

  const size_t SZ = (size_t)BB * HH * NN * DK;  // 2,097,152 elements
  short* q   = (short*)d_ws;
  short* k   = q + SZ;
  short* vt  = k + SZ;
  short* ao  = vt + SZ;
  short* Mm  = ao + SZ;                         // BB*NN*NN bf16 = 16.8 MB
  short* PO  = Mm + (size_t)BB * NN * NN;       // 4*SZ bf16 = 16.8 MB
  float* PL  = (float*)(PO + 4 * SZ);           // 4*BB*HH*NN f32 = 0.5 MB
  short* Xb  = (short*)(PL + 4 * BB * HH * NN); // 4096*512 bf16 = 4.2 MB
  short* Wb  = Xb + (size_t)4096 * DD;          // 4*512*512 bf16 = 2.1 MB

  prep<<<2048, 256, 0, stream>>>(adj, et, ct, Mm, nf, wq, wk, wv, wo, Xb, Wb);
  qkv_gemm<<<768, 256, 0, stream>>>(Xb, Wb, bq, bk, bv, q, k, vt);
  attn_kernel<<<512, 512, 0, stream>>>(q, k, vt, Mm, wt, PO, PL);
  combine<<<1024, 256, 0, stream>>>(PO, PL, ao);
  out_gemm<<<256, 256, 0, stream>>>(ao, Wb + 3 * 262144, bo, nf, (float*)d_out);
}

// Round 19
// 84.845 us; speedup vs baseline: 1.1492x; 1.0867x over previous
//
#include <hip/hip_runtime.h>

#define BB 2
#define NN 2048
#define DD 512
#define HH 8
#define DK 64

#define LOG2E 1.44269504f
#define SCL2  0.18033688f   /* (1/8) * log2e */

typedef __attribute__((ext_vector_type(4))) float f32x4;
typedef __attribute__((ext_vector_type(16))) float f32x16;
typedef __attribute__((ext_vector_type(8))) short bf16x8;
typedef __attribute__((ext_vector_type(2))) int i32x2;
typedef __attribute__((ext_vector_type(4))) int i32x4;

__device__ __forceinline__ short f2bf(float f) {
  union { float f; unsigned u; } v; v.f = f;
  unsigned r = v.u + 0x7fffu + ((v.u >> 16) & 1u);
  return (short)(r >> 16);
}

__device__ __forceinline__ bf16x8 pack8(float4 a, float4 b) {
  bf16x8 r;
  r[0] = f2bf(a.x); r[1] = f2bf(a.y); r[2] = f2bf(a.z); r[3] = f2bf(a.w);
  r[4] = f2bf(b.x); r[5] = f2bf(b.y); r[6] = f2bf(b.z); r[7] = f2bf(b.w);
  return r;
}

#define EXP2R(x) __builtin_amdgcn_exp2f(x)   /* raw v_exp_f32; args bounded */

#define WAITV(n) do { asm volatile("s_waitcnt vmcnt(" #n ")" ::: "memory"); \
                      __builtin_amdgcn_sched_barrier(0); } while (0)
#define GLOAD_LDS(g, l) __builtin_amdgcn_global_load_lds( \
    (const __attribute__((address_space(1))) void*)(g),   \
    (__attribute__((address_space(3))) void*)(l), 16, 0, 0)
#define SBAR() asm volatile("s_barrier" ::: "memory")
#define LDM4(d, o) asm volatile("global_load_dwordx4 %0, %1, off offset:" o \
                                : "=v"(d) : "v"(mrowp))
#define CVTPK(d, a, b) asm("v_cvt_pk_bf16_f32 %0, %1, %2" : "=v"(d) : "v"(a), "v"(b))
#define PLSWAP(a, b) asm("v_permlane32_swap_b32 %0, %1" : "+v"(a), "+v"(b))

// ---------------------------------------------------------------------------
// prep: fused mask_pre + cast_pre (raw v_exp_f32).
// ---------------------------------------------------------------------------
__global__ __launch_bounds__(256) void prep(
    const int* __restrict__ adj, const float* __restrict__ et,
    const int* __restrict__ ctp, short* __restrict__ M,
    const float* __restrict__ X,
    const float* __restrict__ wq, const float* __restrict__ wk,
    const float* __restrict__ wv, const float* __restrict__ wo,
    short* __restrict__ Xb, short* __restrict__ Wb)
{
  const float ct = (float)(*ctp);
  const float kd = -0.1f * LOG2E;
  const size_t base = ((size_t)blockIdx.x * 256 + threadIdx.x) * 8;
  const size_t stride = (size_t)2048 * 256 * 8;   // 4,194,304
#pragma unroll
  for (int it = 0; it < 2; it++) {
    const size_t i = base + (size_t)it * stride;
    int4 a0 = *(const int4*)(adj + i);
    int4 a1 = *(const int4*)(adj + i + 4);
    float4 e0 = *(const float4*)(et + i);
    float4 e1 = *(const float4*)(et + i + 4);
    const int av[8] = {a0.x, a0.y, a0.z, a0.w, a1.x, a1.y, a1.z, a1.w};
    const float ev[8] = {e0.x, e0.y, e0.z, e0.w, e1.x, e1.y, e1.z, e1.w};
    bf16x8 r;
#pragma unroll
    for (int j = 0; j < 8; j++) {
      const float tv = (av[j] == 0) ? -1.f : EXP2R(kd * fmaxf(ct - ev[j], 0.f));
      r[j] = f2bf(tv);
    }
    *(bf16x8*)(M + i) = r;
  }
  if (blockIdx.x < 1536) {
    const size_t XN = (size_t)4096 * DD;          // 2,097,152
    const size_t i = base;
    const float* src;
    short* dst;
    if (i < XN) { src = X + i; dst = Xb + i; }
    else {
      const size_t j = i - XN;
      const int sel = (int)(j >> 18);
      const size_t off = j & 262143;
      src = (sel == 0 ? wq : sel == 1 ? wk : sel == 2 ? wv : wo) + off;
      dst = Wb + j;
    }
    float4 a = *(const float4*)src;
    float4 b = *(const float4*)(src + 4);
    *(bf16x8*)dst = pack8(a, b);
  }
}

// ---------------------------------------------------------------------------
// GEMM1 (R14/R16 structure, unchanged).
// ---------------------------------------------------------------------------
__global__ __launch_bounds__(256, 2) void qkv_gemm(
    const short* __restrict__ Xb, const short* __restrict__ Wb,
    const float* __restrict__ bq, const float* __restrict__ bk, const float* __restrict__ bv,
    short* __restrict__ qo, short* __restrict__ ko, short* __restrict__ vto)
{
  __shared__ short As[2][128 * 64];   // 32 KB
  __shared__ short Bs[2][64 * 64];    // 16 KB

  const int tid = threadIdx.x;
  const int lane = tid & 63;
  const int w = tid >> 6;
  const int q4 = lane >> 4;
  const int c = lane & 15;

  const int bid = blockIdx.x;
  const int mt = bid & 31;
  const int nt = bid >> 5;
  const int sel = nt >> 3;
  const int nw = (nt & 7) * 64;
  const int m0 = mt * 128;
  const short* Wm = Wb + (size_t)sel * 262144;
  const float* bias = sel == 0 ? bq : (sel == 1 ? bk : bv);
  const float oscale = (sel == 0) ? SCL2 : 1.0f;

  const int sr = lane >> 3;
  const int sc = ((lane & 7) ^ sr) * 8;
  const short* ap = Xb + (size_t)(m0 + w * 32 + sr) * DD + sc;
  const short* bp = Wm + (size_t)(nw + w * 16 + sr) * DD + sc;

  f32x4 acc[2][4];
#pragma unroll
  for (int is = 0; is < 2; is++)
#pragma unroll
    for (int ns = 0; ns < 4; ns++) acc[is][ns] = f32x4{0.f, 0.f, 0.f, 0.f};

#define QSTAGE(BUF, K0)                                                    \
  { GLOAD_LDS(ap + (K0),           &As[BUF][(w * 32 + 0) * 64]);           \
    GLOAD_LDS(ap + 8 * DD + (K0),  &As[BUF][(w * 32 + 8) * 64]);           \
    GLOAD_LDS(ap + 16 * DD + (K0), &As[BUF][(w * 32 + 16) * 64]);          \
    GLOAD_LDS(ap + 24 * DD + (K0), &As[BUF][(w * 32 + 24) * 64]);          \
    GLOAD_LDS(bp + (K0),           &Bs[BUF][(w * 16 + 0) * 64]);           \
    GLOAD_LDS(bp + 8 * DD + (K0),  &Bs[BUF][(w * 16 + 8) * 64]); }

#define QCOMPUTE(BUF)                                                            \
  { const short* Asb = &As[BUF][0];                                              \
    const short* Bsb = &Bs[BUF][0];                                              \
    _Pragma("unroll") for (int kc = 0; kc < 2; kc++) {                           \
      bf16x8 af[2], bfr[4];                                                      \
      _Pragma("unroll") for (int is = 0; is < 2; is++)                           \
        af[is] = *(const bf16x8*)&Asb[(w * 32 + is * 16 + c) * 64 +              \
                                      (((kc * 4 + q4) ^ (c & 7)) * 8)];          \
      _Pragma("unroll") for (int ns = 0; ns < 4; ns++)                           \
        bfr[ns] = *(const bf16x8*)&Bsb[(ns * 16 + c) * 64 +                      \
                                       (((kc * 4 + q4) ^ (c & 7)) * 8)];         \
      _Pragma("unroll") for (int is = 0; is < 2; is++)                           \
        _Pragma("unroll") for (int ns = 0; ns < 4; ns++)                         \
          acc[is][ns] = __builtin_amdgcn_mfma_f32_16x16x32_bf16(af[is], bfr[ns], \
                                                           acc[is][ns], 0, 0, 0); \
    } }

  QSTAGE(0, 0)
  __syncthreads();
  for (int ks = 0; ks < 8; ks++) {
    if (ks < 7) QSTAGE((ks + 1) & 1, (ks + 1) * 64)
    QCOMPUTE(ks & 1)
    __syncthreads();
  }
#undef QSTAGE
#undef QCOMPUTE

#pragma unroll
  for (int ns = 0; ns < 4; ns++) {
    const int n = nw + ns * 16 + c;
    const float bval = bias[n];
    const int hh = n >> 6, d = n & 63;
#pragma unroll
    for (int is = 0; is < 2; is++)
#pragma unroll
      for (int r = 0; r < 4; r++) {
        const int m = m0 + w * 32 + is * 16 + q4 * 4 + r;
        const int bb = m >> 11, tok = m & 2047;
        const float val = (acc[is][ns][r] + bval) * oscale;
        if (sel == 2)      vto[((size_t)(bb * HH + hh) * DK + d) * NN + tok] = f2bf(val);
        else if (sel == 1) ko [((size_t)(bb * HH + hh) * NN + tok) * DK + d] = f2bf(val);
        else               qo [((size_t)(bb * HH + hh) * NN + tok) * DK + d] = f2bf(val);
      }
  }
}

// ---------------------------------------------------------------------------
// Flash attention: R18 structure + raw v_exp_f32 + 4-way split lp chains.
// ---------------------------------------------------------------------------
__global__ __launch_bounds__(512, 2) void attn_kernel(
    const short* __restrict__ qt, const short* __restrict__ kt, const short* __restrict__ vtt,
    const short* __restrict__ M,
    const float* __restrict__ wt,
    short* __restrict__ po_out, float* __restrict__ pl_out)
{
  __shared__ short Ks[2][128 * 64];   // 32 KB (K tile dbuf: 128 j-rows x 64 dk)
  __shared__ short Vs[2][64 * 128];   // 32 KB (V^T tile dbuf: 64 dk-rows x 128 j)

  const int tid = threadIdx.x;
  const int lane = tid & 63;
  const int w = tid >> 6;          // wave 0..7
  const int l31 = lane & 31;
  const int hi = lane >> 5;
  const int l7 = l31 & 7;

  // decode: xcd = bid&7 = b*4 + jsp; rest: h (0..7), qblk (0..7)
  const int bid = blockIdx.x;
  const int xcd = bid & 7;
  const int b = xcd >> 2;
  const int jsp = xcd & 3;
  const int rest = bid >> 3;        // 0..63
  const int h = rest & 7;
  const int qblk = rest >> 3;       // 0..7
  const int i0w = qblk * 256 + w * 32;
  const int jbase = jsp * 512;

  const float wth2 = wt[h] * LOG2E;

  const short* qb = qt + ((size_t)(b * HH + h) * NN + i0w) * DK;
  const short* kb = kt + (size_t)(b * HH + h) * NN * DK;
  const short* vb = vtt + (size_t)(b * HH + h) * DK * NN;
  const short* mrowp = M + ((size_t)b * NN + i0w + l31) * NN + jbase + hi * 4;

  // Q fragments (B operand): col i = l31, k = kc*16 + hi*8 + e
  bf16x8 aq[4];
#pragma unroll
  for (int kc = 0; kc < 4; kc++)
    aq[kc] = *(const bf16x8*)(qb + l31 * DK + kc * 16 + hi * 8);
  asm volatile("" :: "v"(aq[0]), "v"(aq[1]), "v"(aq[2]), "v"(aq[3]), "v"(wth2));
  WAITV(0);   // drain compiler-issued loads; counted sequence starts clean

  // hoisted LDS read byte-offsets (loop-invariant)
  unsigned ka[4];
#pragma unroll
  for (int kc = 0; kc < 4; kc++)
    ka[kc] = (unsigned)(l31 * 128 + (((kc * 2 + hi) ^ l7) * 16));
  unsigned va2[8];
#pragma unroll
  for (int jc = 0; jc < 8; jc++) {   // jc = js*2 + ch, js 0..3
    const int js = jc >> 1, ch = jc & 1;
    va2[jc] = (unsigned)(l31 * 256 + (((js * 4 + ch * 2 + hi) ^ (l31 & 15)) * 16));
  }

  float lp4[4];
#pragma unroll
  for (int u = 0; u < 4; u++) lp4[u] = 0.f;
  f32x16 oacc[2];
#pragma unroll
  for (int ds = 0; ds < 2; ds++)
#pragma unroll
    for (int r = 0; r < 16; r++) oacc[ds][r] = 0.f;

  // staging sources (pre-swizzled)
  const int kr = w * 16 + (lane >> 3);           // K j-row within tile
  const short* kp0 = kb + (size_t)(jbase + kr) * DK + (((lane & 7) ^ (kr & 7)) * 8);
  const short* kp1 = kp0 + 8 * DK;               // (kr+8)&7 == kr&7
  const int vr = w * 8 + (lane >> 4);            // V^T dk-row
  const short* vp0 = vb + (size_t)vr * NN + jbase + (((lane & 15) ^ (vr & 15)) * 8);
  const short* vp1 = vb + (size_t)(vr + 4) * NN + jbase + (((lane & 15) ^ ((vr + 4) & 15)) * 8);
  const char* KsB = (const char*)&Ks[0][0];
  const char* VsB = (const char*)&Vs[0][0];

#define STAGE(BUFN)                                                        \
  { GLOAD_LDS(kp0, &Ks[BUFN][(w * 16) * 64]);                              \
    GLOAD_LDS(kp1, &Ks[BUFN][(w * 16 + 8) * 64]);                          \
    GLOAD_LDS(vp0, &Vs[BUFN][(w * 8) * 128]);                              \
    GLOAD_LDS(vp1, &Vs[BUFN][(w * 8 + 4) * 128]);                          \
    __builtin_amdgcn_sched_barrier(0); }

#define KADV() { kp0 += 128 * DK; kp1 += 128 * DK; vp0 += 128; vp1 += 128; }
#define MADV() { mrowp += 128; }

// masks: 4 x dwordx4 per half; MU[jj][qq] covers q = 2qq, 2qq+1
#define ISSUE_MASK_H0(MU)                                                  \
  { LDM4(MU[0][0], "0");   LDM4(MU[0][1], "32");                           \
    LDM4(MU[1][0], "64");  LDM4(MU[1][1], "96");                           \
    __builtin_amdgcn_sched_barrier(0); }
#define ISSUE_MASK_H1(MU)                                                  \
  { LDM4(MU[0][0], "128"); LDM4(MU[0][1], "160");                          \
    LDM4(MU[1][0], "192"); LDM4(MU[1][1], "224");                          \
    __builtin_amdgcn_sched_barrier(0); }

  i32x4 muA[2][2], muB[2][2];

  // prologue: stage tile0 [4] + masks tile0-half0 [4]; drain stage; barrier
  STAGE(0)
  KADV()
  ISSUE_MASK_H0(muA)
  WAITV(4);
  SBAR();

#define COMPUTE_QK(BUFC, JS0)                                                    \
    __builtin_amdgcn_s_setprio(1);                                               \
    _Pragma("unroll") for (int jj = 0; jj < 2; jj++) {                           \
      _Pragma("unroll") for (int r = 0; r < 16; r++) sacc[jj][r] = 0.f;          \
      _Pragma("unroll") for (int kc = 0; kc < 4; kc++) {                         \
        bf16x8 kf = *(const bf16x8*)(KsB + (BUFC) * 16384 +                      \
                                     ((JS0) + jj) * 4096 + ka[kc]);              \
        sacc[jj] = __builtin_amdgcn_mfma_f32_32x32x16_bf16(kf, aq[kc],           \
                                                           sacc[jj], 0, 0, 0);   \
      }                                                                          \
    }                                                                            \
    __builtin_amdgcn_s_setprio(0);

#define COMPUTE_SM_PV(BUFC, MU, JS0)                                             \
    __builtin_amdgcn_s_setprio(1);                                               \
    _Pragma("unroll") for (int jj = 0; jj < 2; jj++) {                           \
      float p[16];                                                               \
      _Pragma("unroll") for (int r = 0; r < 16; r++) {                           \
        const int q = r >> 2;                                                    \
        const int dw = MU[jj][q >> 1][(q & 1) * 2 + ((r & 3) >> 1)];             \
        union { float f; unsigned u; } tu;                                       \
        tu.u = (r & 1) ? ((unsigned)dw & 0xffff0000u) : ((unsigned)dw << 16);    \
        const float tv = tu.f;                                                   \
        const float pp = EXP2R(fmaf(tv, wth2, sacc[jj][r]));                     \
        p[r] = (tv < 0.f) ? 0.f : pp;                                            \
        lp4[r >> 2] += p[r];                                                     \
      }                                                                          \
      bf16x8 pf[2];                                                              \
      _Pragma("unroll") for (int ch = 0; ch < 2; ch++) {                         \
        const int rb = ch * 8;                                                   \
        int w0, w1, w2, w3;                                                      \
        CVTPK(w0, p[rb + 0], p[rb + 1]);                                         \
        CVTPK(w1, p[rb + 2], p[rb + 3]);                                         \
        CVTPK(w2, p[rb + 4], p[rb + 5]);                                         \
        CVTPK(w3, p[rb + 6], p[rb + 7]);                                         \
        PLSWAP(w0, w2);                                                          \
        PLSWAP(w1, w3);                                                          \
        i32x4 bi;                                                                \
        bi[0] = w0; bi[1] = w1; bi[2] = w2; bi[3] = w3;                          \
        union { i32x4 i; bf16x8 h; } cv; cv.i = bi;                              \
        pf[ch] = cv.h;                                                           \
      }                                                                          \
      _Pragma("unroll") for (int ds = 0; ds < 2; ds++) {                         \
        _Pragma("unroll") for (int ch = 0; ch < 2; ch++) {                       \
          bf16x8 vf = *(const bf16x8*)(VsB + (BUFC) * 16384 + ds * 8192 +        \
                                       va2[((JS0) + jj) * 2 + ch]);              \
          oacc[ds] = __builtin_amdgcn_mfma_f32_32x32x16_bf16(vf, pf[ch],         \
                                                             oacc[ds], 0, 0, 0); \
        }                                                                        \
      }                                                                          \
    }                                                                            \
    __builtin_amdgcn_s_setprio(0);

  // iteration (entry: [muA:4], buf T&1 staged+visible); ONE barrier per tile
#define ATTN_ITER(T, LASTI)                                                      \
  {                                                                              \
    f32x16 sacc[2];                                                              \
    if (!(LASTI)) { STAGE(((T) + 1) & 1) KADV() }   /* [muA:4, S:4] */           \
    COMPUTE_QK((T) & 1, 0)                                                       \
    ISSUE_MASK_H1(muB)            /* [muA:4, S:4, muB:4] = 12 (last: 8) */       \
    if (LASTI) { WAITV(4); } else { WAITV(8); }      /* drain muA */             \
    COMPUTE_SM_PV((T) & 1, muA, 0)                                               \
    COMPUTE_QK((T) & 1, 2)                                                       \
    if (!(LASTI)) { MADV() ISSUE_MASK_H0(muA) }  /* [S:4, muB:4, muA':4] */      \
    if (LASTI) { WAITV(0); } else { WAITV(4); }      /* drain S + muB */         \
    COMPUTE_SM_PV((T) & 1, muB, 2)                                               \
    if (!(LASTI)) { SBAR(); }                                                    \
  }

  ATTN_ITER(0, 0)
  ATTN_ITER(1, 0)
  ATTN_ITER(2, 0)
  ATTN_ITER(3, 1)

#undef ATTN_ITER
#undef COMPUTE_QK
#undef COMPUTE_SM_PV
#undef STAGE
#undef KADV
#undef MADV
#undef ISSUE_MASK_H0
#undef ISSUE_MASK_H1

  // epilogue: partial row sum; packed dwordx2 stores of UNNORMALIZED O^T
  const float lp = (lp4[0] + lp4[1]) + (lp4[2] + lp4[3]);
  const float lt = lp + __shfl_xor(lp, 32);
  const size_t ridx = ((size_t)(jsp * BB + b) * HH + h) * NN + i0w + l31;
  if (lane < 32) pl_out[ridx] = lt;
  short* pob = po_out + ridx * DK;
#pragma unroll
  for (int ds = 0; ds < 2; ds++)
#pragma unroll
    for (int q = 0; q < 4; q++) {
      int d0, d1;
      CVTPK(d0, oacc[ds][q * 4 + 0], oacc[ds][q * 4 + 1]);
      CVTPK(d1, oacc[ds][q * 4 + 2], oacc[ds][q * 4 + 3]);
      i32x2 pk; pk[0] = d0; pk[1] = d1;
      *(i32x2*)(pob + ds * 32 + q * 8 + hi * 4) = pk;
    }
}

// ---------------------------------------------------------------------------
// combine: AO[b][n][h*64+d] = sum_jsp PO / sum_jsp PL   (4 partials)
// ---------------------------------------------------------------------------
__global__ __launch_bounds__(256) void combine(
    const short* __restrict__ PO, const float* __restrict__ PL,
    short* __restrict__ AO)
{
  const int g = blockIdx.x * 256 + threadIdx.x;     // 0..262143
  const int t8 = g & 7;
  const int h  = (g >> 3) & 7;
  const int n  = (g >> 6) & 2047;
  const int b  = g >> 17;
  float acc[8] = {0.f, 0.f, 0.f, 0.f, 0.f, 0.f, 0.f, 0.f};
  float ls = 0.f;
#pragma unroll
  for (int jp = 0; jp < 4; jp++) {
    const size_t ridx = ((size_t)(jp * BB + b) * HH + h) * NN + n;
    bf16x8 v = *(const bf16x8*)(PO + ridx * DK + t8 * 8);
    ls += PL[ridx];
#pragma unroll
    for (int e = 0; e < 8; e++) {
      union { float f; unsigned u; } cv;
      cv.u = ((unsigned)(unsigned short)v[e]) << 16;
      acc[e] += cv.f;
    }
  }
  const float rl = 1.0f / ls;
  bf16x8 o;
#pragma unroll
  for (int e = 0; e < 8; e++) o[e] = f2bf(acc[e] * rl);
  *(bf16x8*)(AO + (size_t)g * 8) = o;
}

// ---------------------------------------------------------------------------
// GEMM2 (R14/R16 structure, unchanged).
// ---------------------------------------------------------------------------
__global__ __launch_bounds__(256, 2) void out_gemm(
    const short* __restrict__ AO, const short* __restrict__ wob, const float* __restrict__ bo,
    const float* __restrict__ nf, float* __restrict__ out)
{
  __shared__ short As[2][128 * 64];   // 32 KB
  __shared__ short Bs[2][64 * 64];    // 16 KB

  const int tid = threadIdx.x;
  const int lane = tid & 63;
  const int w = tid >> 6;
  const int q4 = lane >> 4;
  const int c = lane & 15;

  const int bid = blockIdx.x;
  const int mt = bid & 31;
  const int n0 = (bid >> 5) * 64;
  const int m0 = mt * 128;

  const int sr = lane >> 3;
  const int sc = ((lane & 7) ^ sr) * 8;
  const short* ap = AO + (size_t)(m0 + w * 32 + sr) * DD + sc;
  const short* bp = wob + (size_t)(n0 + w * 16 + sr) * DD + sc;

  f32x4 acc[2][4];
#pragma unroll
  for (int is = 0; is < 2; is++)
#pragma unroll
    for (int ns = 0; ns < 4; ns++) acc[is][ns] = f32x4{0.f, 0.f, 0.f, 0.f};

#define OSTAGE(BUF, K0)                                                    \
  { GLOAD_LDS(ap + (K0),           &As[BUF][(w * 32 + 0) * 64]);           \
    GLOAD_LDS(ap + 8 * DD + (K0),  &As[BUF][(w * 32 + 8) * 64]);           \
    GLOAD_LDS(ap + 16 * DD + (K0), &As[BUF][(w * 32 + 16) * 64]);          \
    GLOAD_LDS(ap + 24 * DD + (K0), &As[BUF][(w * 32 + 24) * 64]);          \
    GLOAD_LDS(bp + (K0),           &Bs[BUF][(w * 16 + 0) * 64]);           \
    GLOAD_LDS(bp + 8 * DD + (K0),  &Bs[BUF][(w * 16 + 8) * 64]); }

#define OCOMPUTE(BUF)                                                            \
  { const short* Asb = &As[BUF][0];                                              \
    const short* Bsb = &Bs[BUF][0];                                              \
    _Pragma("unroll") for (int kc = 0; kc < 2; kc++) {                           \
      bf16x8 af[2], bfr[4];                                                      \
      _Pragma("unroll") for (int is = 0; is < 2; is++)                           \
        af[is] = *(const bf16x8*)&Asb[(w * 32 + is * 16 + c) * 64 +              \
                                      (((kc * 4 + q4) ^ (c & 7)) * 8)];          \
      _Pragma("unroll") for (int ns = 0; ns < 4; ns++)                           \
        bfr[ns] = *(const bf16x8*)&Bsb[(ns * 16 + c) * 64 +                      \
                                       (((kc * 4 + q4) ^ (c & 7)) * 8)];         \
      _Pragma("unroll") for (int is = 0; is < 2; is++)                           \
        _Pragma("unroll") for (int ns = 0; ns < 4; ns++)                         \
          acc[is][ns] = __builtin_amdgcn_mfma_f32_16x16x32_bf16(af[is], bfr[ns], \
                                                           acc[is][ns], 0, 0, 0); \
    } }

  OSTAGE(0, 0)
  __syncthreads();
  for (int ks = 0; ks < 8; ks++) {
    if (ks < 7) OSTAGE((ks + 1) & 1, (ks + 1) * 64)
    OCOMPUTE(ks & 1)
    __syncthreads();
  }
#undef OSTAGE
#undef OCOMPUTE

#pragma unroll
  for (int ns = 0; ns < 4; ns++) {
    const int n = n0 + ns * 16 + c;
    const float bval = bo[n];
#pragma unroll
    for (int is = 0; is < 2; is++)
#pragma unroll
      for (int r = 0; r < 4; r++) {
        const int m = m0 + w * 32 + is * 16 + q4 * 4 + r;
        out[(size_t)m * DD + n] = acc[is][ns][r] + bval + nf[(size_t)m * DD + n];
      }
  }
}

extern "C" void kernel_launch(void* const* d_in, const int* in_sizes, int n_in,
                              void* d_out, int out_size, void* d_ws, size_t ws_size,
                              hipStream_t stream) {
  const float* nf  = (const float*)d_in[0];
  const int*   adj = (const int*)d_in[1];
  const float* et  = (const float*)d_in[2];
  const int*   ct  = (const int*)d_in[3];
  const float* wq  = (const float*)d_in[4];
  const float* bq  = (const float*)d_in[5];
  const float* wk  = (const float*)d_in[6];
  const float* bk  = (const float*)d_in[7];
  const float* wv  = (const float*)d_in[8];
  const float* bv  = (const float*)d_in[9];
  const float* wo  = (const float*)d_in[10];
  const float* bo  = (const float*)d_in[11];
  const float* wt  = (const float*)d_in[12];

  const size_t SZ = (size_t)BB * HH * NN * DK;  // 2,097,152 elements
  short* q   = (short*)d_ws;
  short* k   = q + SZ;
  short* vt  = k + SZ;
  short* ao  = vt + SZ;
  short* Mm  = ao + SZ;                         // BB*NN*NN bf16 = 16.8 MB
  short* PO  = Mm + (size_t)BB * NN * NN;       // 4*SZ bf16 = 16.8 MB
  float* PL  = (float*)(PO + 4 * SZ);           // 4*BB*HH*NN f32 = 0.5 MB
  short* Xb  = (short*)(PL + 4 * BB * HH * NN); // 4096*512 bf16 = 4.2 MB
  short* Wb  = Xb + (size_t)4096 * DD;          // 4*512*512 bf16 = 2.1 MB

  prep<<<2048, 256, 0, stream>>>(adj, et, ct, Mm, nf, wq, wk, wv, wo, Xb, Wb);
  qkv_gemm<<<768, 256, 0, stream>>>(Xb, Wb, bq, bk, bv, q, k, vt);
  attn_kernel<<<512, 512, 0, stream>>>(q, k, vt, Mm, wt, PO, PL);
  combine<<<1024, 256, 0, stream>>>(PO, PL, ao);
  out_gemm<<<256, 256, 0, stream>>>(ao, Wb + 3 * 262144, bo, nf, (float*)d_out);
}